// Round 2
// baseline (29766.937 us; speedup 1.0000x reference)
//
// Round 2: correctness-first full pipeline, ws < 128 MiB.
// Key decisions:
//  - All large activations bf16 (seq/xz/xc), GEMM accum fp32 -> ws 116.3 MiB
//    (round-1 407 MB fp32 plan is the suspected OOB-fault cause).
//  - dt stored fp16 over the dead x-half of xz (bf16 dt would put ~4% error
//    into exp(dt*A)); scan writes y bf16 in place over dt (dt[t] consumed and
//    dt[t+1] prefetched before y[t] store; wave-lockstep makes this safe).
//  - hbuf aliases xc (dead after scan).
#include <hip/hip_runtime.h>
#include <hip/hip_bf16.h>
#include <hip/hip_fp16.h>
#include <math.h>

#define B_ 8
#define S_ 2048
#define H_ 512
#define DI_ 1024
#define DS_ 16
#define DC_ 4
#define DR_ 32
#define NL_ 8

typedef __hip_bfloat16 bf16;

static __device__ __forceinline__ float wred_sum(float v) {
#pragma unroll
  for (int o = 32; o; o >>= 1) v += __shfl_down(v, o, 64);
  return v;
}

static __device__ __forceinline__ float bf2f(unsigned short u) {
  return __uint_as_float(((unsigned)u) << 16);
}
static __device__ __forceinline__ void ld4(const float* p, float* o) {
  float4 v = *(const float4*)p;
  o[0] = v.x; o[1] = v.y; o[2] = v.z; o[3] = v.w;
}
static __device__ __forceinline__ void ld4(const bf16* p, float* o) {
  ushort4 v = *reinterpret_cast<const ushort4*>(p);
  o[0] = bf2f(v.x); o[1] = bf2f(v.y); o[2] = bf2f(v.z); o[3] = bf2f(v.w);
}
static __device__ __forceinline__ void st1(float* p, float v) { *p = v; }
static __device__ __forceinline__ void st1(bf16* p, float v) { *p = __float2bfloat16(v); }
static __device__ __forceinline__ void st1(__half* p, float v) { *p = __float2half(v); }

// ---------------- K1: embedding + LN + gate ----------------
__global__ void k_embed(const int* __restrict__ ids, const float* __restrict__ gate,
                        const float* __restrict__ wemb, const float* __restrict__ pos2,
                        const float* __restrict__ pe, const float* __restrict__ g,
                        const float* __restrict__ bta, bf16* __restrict__ seq) {
  int row = blockIdx.x;  // b*S + s
  int s = row % S_;
  int t = threadIdx.x;   // 256
  int id = ids[row];
  float v[2];
#pragma unroll
  for (int i = 0; i < 2; i++) {
    int h = t + i * 256;
    v[i] = pos2[s * H_ + h] * wemb[(long)id * H_ + h] + pe[s * H_ + h];
  }
  float lsum = v[0] + v[1];
  float lsq = v[0] * v[0] + v[1] * v[1];
  __shared__ float smA[4], smB[4];
  int lane = t & 63, w = t >> 6;
  lsum = wred_sum(lsum);
  lsq = wred_sum(lsq);
  if (!lane) { smA[w] = lsum; smB[w] = lsq; }
  __syncthreads();
  float tot = smA[0] + smA[1] + smA[2] + smA[3];
  float totq = smB[0] + smB[1] + smB[2] + smB[3];
  float mu = tot * (1.f / H_);
  float var = totq * (1.f / H_) - mu * mu;
  float inv = rsqrtf(fmaxf(var, 0.f) + 1e-12f);
  float gt = gate[row];
#pragma unroll
  for (int i = 0; i < 2; i++) {
    int h = t + i * 256;
    st1(&seq[(long)row * H_ + h], gt * (g[h] * (v[i] - mu) * inv + bta[h]));
  }
}

// ---------------- generic tiled GEMM: C[M,N] = X[M,K] @ W[N,K]^T ----------------
// ACT: 0 = none, 1 = bias + softplus
template <int ACT, int BT, typename TX, typename TC>
__global__ void k_gemm(const TX* __restrict__ X, int lda,
                       const float* __restrict__ W, int ldb,
                       const float* __restrict__ bias,
                       TC* __restrict__ C, int ldc, int K) {
  constexpr int MT = BT / 16;  // 4 or 8
  __shared__ float Xs[BT][17];
  __shared__ float Ws[BT][17];
  int tid = threadIdx.x;
  int tx = tid & 15, ty = tid >> 4;
  long row0 = (long)blockIdx.y * BT;
  long col0 = (long)blockIdx.x * BT;
  float acc[MT][MT] = {};
  int lr = tid >> 2;       // 0..63
  int lk = (tid & 3) * 4;  // 0,4,8,12
  for (int k0 = 0; k0 < K; k0 += 16) {
#pragma unroll
    for (int r = 0; r < BT; r += 64) {
      float xv[4], wv[4];
      ld4(X + (row0 + lr + r) * (long)lda + k0 + lk, xv);
      ld4(W + (col0 + lr + r) * (long)ldb + k0 + lk, wv);
#pragma unroll
      for (int q = 0; q < 4; q++) {
        Xs[lr + r][lk + q] = xv[q];
        Ws[lr + r][lk + q] = wv[q];
      }
    }
    __syncthreads();
#pragma unroll
    for (int kk = 0; kk < 16; kk++) {
      float a[MT], bb[MT];
#pragma unroll
      for (int i = 0; i < MT; i++) a[i] = Xs[ty * MT + i][kk];
#pragma unroll
      for (int j = 0; j < MT; j++) bb[j] = Ws[tx * MT + j][kk];
#pragma unroll
      for (int i = 0; i < MT; i++)
#pragma unroll
        for (int j = 0; j < MT; j++) acc[i][j] += a[i] * bb[j];
    }
    __syncthreads();
  }
#pragma unroll
  for (int i = 0; i < MT; i++) {
#pragma unroll
    for (int j = 0; j < MT; j++) {
      long r = row0 + ty * MT + i;
      long c = col0 + tx * MT + j;
      float v = acc[i][j];
      if constexpr (ACT == 1) {
        v += bias[c];
        v = fmaxf(v, 0.f) + log1pf(__expf(-fabsf(v)));  // softplus
      }
      st1(&C[r * (long)ldc + c], v);
    }
  }
}

// ---------------- conv (depthwise causal, DC=4) + silu ----------------
__global__ void k_conv(const bf16* __restrict__ xz, const float* __restrict__ cw,
                       const float* __restrict__ cb, bf16* __restrict__ xc) {
  long idx = (long)blockIdx.x * 256 + threadIdx.x;  // < B*S*DI
  int d = (int)(idx & 1023);
  long bt = idx >> 10;  // b*S + t
  int t = (int)(bt & 2047);
  const unsigned short* xbase =
      (const unsigned short*)xz + (bt - t) * 2048 + d;  // x-half, col d
  float acc = cb[d];
#pragma unroll
  for (int k = 0; k < 4; k++) {
    int ts = t + k - 3;
    if (ts >= 0) acc += cw[d * 4 + k] * bf2f(xbase[(long)ts * 2048]);
  }
  float s = acc / (1.f + __expf(-acc));  // silu
  st1(&xc[idx], s);
}

// ---------------- selective scan: 2 lanes per (b,d), 8 states each ----------------
// dt is fp16 in the x-half of xz (stride 2048); z is bf16 in the z-half;
// y (bf16) is written in place over dt.
__global__ void __launch_bounds__(64) k_scan(
    bf16* __restrict__ xzb, const bf16* __restrict__ xc,
    const float* __restrict__ xdb, const float* __restrict__ Alog,
    const float* __restrict__ Dp) {
  int idx = blockIdx.x * 64 + threadIdx.x;  // 0..16383
  int half = idx & 1;
  int p = idx >> 1;
  int d = p & 1023;
  int b = p >> 10;
  int n0 = half * 8;
  float A[8];
#pragma unroll
  for (int n = 0; n < 8; n++) A[n] = -__expf(Alog[d * 16 + n0 + n]);
  float Dd = Dp[d];
  float h[8] = {0, 0, 0, 0, 0, 0, 0, 0};
  const __half* dtb = (const __half*)xzb + (long)b * S_ * 2048 + d;
  const unsigned short* xb = (const unsigned short*)xc + (long)b * S_ * DI_ + d;
  const unsigned short* zb = (const unsigned short*)xzb + (long)b * S_ * 2048 + DI_ + d;
  const float* bcb = xdb + (long)b * S_ * 64 + DR_ + n0;
  bf16* yb = xzb + (long)b * S_ * 2048 + d;
  // preload t=0
  float dt_c = __half2float(dtb[0]);
  float x_c = bf2f(xb[0]);
  float z_c = bf2f(zb[0]);
  float Bc[8], Cc[8];
#pragma unroll
  for (int n = 0; n < 8; n++) { Bc[n] = bcb[n]; Cc[n] = bcb[16 + n]; }
  for (int t = 0; t < S_; t++) {
    float dt_n = 0.f, x_n = 0.f, z_n = 0.f, Bn[8], Cn[8];
#pragma unroll
    for (int n = 0; n < 8; n++) { Bn[n] = 0.f; Cn[n] = 0.f; }
    if (t + 1 < S_) {
      long o = (long)(t + 1);
      dt_n = __half2float(dtb[o * 2048]);
      x_n = bf2f(xb[o * DI_]);
      z_n = bf2f(zb[o * 2048]);
      const float* bc = bcb + o * 64;
#pragma unroll
      for (int n = 0; n < 8; n++) { Bn[n] = bc[n]; Cn[n] = bc[16 + n]; }
    }
    float dx = dt_c * x_c;
    float yacc = 0.f;
#pragma unroll
    for (int n = 0; n < 8; n++) {
      float hn = __expf(dt_c * A[n]) * h[n] + dx * Bc[n];
      h[n] = hn;
      yacc += hn * Cc[n];
    }
    yacc += __shfl_xor(yacc, 1, 64);
    if (!half) {
      float sz = z_c / (1.f + __expf(-z_c));
      st1(&yb[(long)t * 2048], (yacc + Dd * x_c) * sz);
    }
    dt_c = dt_n; x_c = x_n; z_c = z_n;
#pragma unroll
    for (int n = 0; n < 8; n++) { Bc[n] = Bn[n]; Cc[n] = Cn[n]; }
  }
}

// ---------------- residual + LN + gate (in-place on seq) ----------------
__global__ void k_resid_ln(const bf16* __restrict__ hb, const float* __restrict__ gate,
                           const float* __restrict__ g, const float* __restrict__ bta,
                           bf16* __restrict__ seq) {
  int row = blockIdx.x;
  int t = threadIdx.x;  // 256
  float v[2];
#pragma unroll
  for (int i = 0; i < 2; i++) {
    int h = t + i * 256;
    v[i] = bf2f(((const unsigned short*)hb)[(long)row * H_ + h]) +
           bf2f(((const unsigned short*)seq)[(long)row * H_ + h]);
  }
  float lsum = v[0] + v[1];
  float lsq = v[0] * v[0] + v[1] * v[1];
  __shared__ float smA[4], smB[4];
  int lane = t & 63, w = t >> 6;
  lsum = wred_sum(lsum);
  lsq = wred_sum(lsq);
  if (!lane) { smA[w] = lsum; smB[w] = lsq; }
  __syncthreads();
  float tot = smA[0] + smA[1] + smA[2] + smA[3];
  float totq = smB[0] + smB[1] + smB[2] + smB[3];
  float mu = tot * (1.f / H_);
  float var = totq * (1.f / H_) - mu * mu;
  float inv = rsqrtf(fmaxf(var, 0.f) + 1e-12f);
  float gt = gate[row];
#pragma unroll
  for (int i = 0; i < 2; i++) {
    int h = t + i * 256;
    st1(&seq[(long)row * H_ + h], gt * (g[h] * (v[i] - mu) * inv + bta[h]));
  }
}

// ---------------- max pool (two stage) ----------------
__global__ void k_pool1(const bf16* __restrict__ seq, const float* __restrict__ gate,
                        float* __restrict__ part) {
  int blk = blockIdx.x;  // B*16
  int b = blk >> 4, c = blk & 15;
  int h = threadIdx.x;   // 512
  float m = -3.4e38f;
  for (int i = 0; i < 128; i++) {
    long r = (long)b * S_ + c * 128 + i;
    m = fmaxf(m, bf2f(((const unsigned short*)seq)[r * H_ + h]) * gate[r]);
  }
  part[((long)b * 16 + c) * H_ + h] = m;
}
__global__ void k_pool2(const float* __restrict__ part, float* __restrict__ pooled) {
  int idx = blockIdx.x * 256 + threadIdx.x;  // 4096
  int b = idx >> 9, h = idx & 511;
  float m = -3.4e38f;
#pragma unroll
  for (int c = 0; c < 16; c++) m = fmaxf(m, part[((long)b * 16 + c) * H_ + h]);
  pooled[idx] = m;
}

// ---------------- dense2 + gelu_new ----------------
__global__ void k_feat(const float* __restrict__ pooled, const float* __restrict__ W2,
                       const float* __restrict__ b2, float* __restrict__ feat) {
  int b = blockIdx.x;
  int j = threadIdx.x;  // 512
  __shared__ float ps[512];
  ps[j] = pooled[b * 512 + j];
  __syncthreads();
  float acc = b2[j];
  const float* wr = W2 + (long)j * 512;
  for (int k = 0; k < 512; k++) acc += ps[k] * wr[k];
  float x = acc;
  float u = 0.7978845608028654f * (x + 0.044715f * x * x * x);
  feat[b * 512 + j] = 0.5f * x * (1.f + tanhf(u));
}

// ---------------- GroupNorm + FiLM(style) + head ----------------
__global__ void k_head(const float* __restrict__ feat, const float* __restrict__ age_sex,
                       const float* __restrict__ mw, const float* __restrict__ mb,
                       const float* __restrict__ gng, const float* __restrict__ gnb,
                       const float* __restrict__ hw, const float* __restrict__ hb,
                       float* __restrict__ out) {
  int b = blockIdx.x;
  int j = threadIdx.x;  // 512
  float f = feat[b * 512 + j];
  __shared__ float sA[8], sB[8];
  int lane = j & 63, w = j >> 6;
  float s1 = wred_sum(f);
  float s2 = wred_sum(f * f);
  if (!lane) { sA[w] = s1; sB[w] = s2; }
  __syncthreads();
  int g = j >> 7;  // 4 groups of 128 = 2 waves each
  float tot = sA[2 * g] + sA[2 * g + 1];
  float totq = sB[2 * g] + sB[2 * g + 1];
  float mu = tot * (1.f / 128.f);
  float var = totq * (1.f / 128.f) - mu * mu;
  float gn = (f - mu) * rsqrtf(fmaxf(var, 0.f) + 1e-5f) * gng[j] + gnb[j];
  float a0 = age_sex[b * 2], a1 = age_sex[b * 2 + 1];
  float sa = a0 * mw[j * 2] + a1 * mw[j * 2 + 1] + mb[j];
  sa = sa > 0.f ? sa : (__expf(sa) - 1.f);  // elu
  int j2 = 512 + j;
  float sb = a0 * mw[j2 * 2] + a1 * mw[j2 * 2 + 1] + mb[j2];
  sb = sb > 0.f ? sb : (__expf(sb) - 1.f);
  float feature = (1.f + sa) * gn + sb;
  out[16 + 16384 + b * 512 + j] = feature;
  float l0 = feature * hw[j];
  float l1 = feature * hw[512 + j];
  __syncthreads();
  l0 = wred_sum(l0);
  l1 = wred_sum(l1);
  if (!lane) { sA[w] = l0; sB[w] = l1; }
  __syncthreads();
  if (j == 0) {
    float t0 = 0.f, t1 = 0.f;
#pragma unroll
    for (int i = 0; i < 8; i++) { t0 += sA[i]; t1 += sB[i]; }
    out[b * 2 + 0] = t0 + hb[0];
    out[b * 2 + 1] = t1 + hb[1];
  }
}

// ---------------- gate passthrough copy ----------------
__global__ void k_copy(const float* __restrict__ src, float* __restrict__ dst, int n) {
  int i = blockIdx.x * 256 + threadIdx.x;
  if (i < n) dst[i] = src[i];
}

// ---------------- launch ----------------
extern "C" void kernel_launch(void* const* d_in, const int* in_sizes, int n_in,
                              void* d_out, int out_size, void* d_ws, size_t ws_size,
                              hipStream_t stream) {
  const int* ids = (const int*)d_in[0];
  const float* gate = (const float*)d_in[1];
  const float* age_sex = (const float*)d_in[2];
  const float* word_emb = (const float*)d_in[3];
  const float* pos_emb2 = (const float*)d_in[4];
  const float* pe = (const float*)d_in[5];
  const float* emb_ln_g = (const float*)d_in[6];
  const float* emb_ln_b = (const float*)d_in[7];
  const float* in_proj_w = (const float*)d_in[8];
  const float* conv_w = (const float*)d_in[9];
  const float* conv_b = (const float*)d_in[10];
  const float* x_proj_w = (const float*)d_in[11];
  const float* dt_proj_w = (const float*)d_in[12];
  const float* dt_proj_b = (const float*)d_in[13];
  const float* A_log = (const float*)d_in[14];
  const float* D_param = (const float*)d_in[15];
  const float* out_proj_w = (const float*)d_in[16];
  const float* blk_ln_g = (const float*)d_in[17];
  const float* blk_ln_b = (const float*)d_in[18];
  const float* dense2_w = (const float*)d_in[19];
  const float* dense2_b = (const float*)d_in[20];
  const float* male_fc_w = (const float*)d_in[21];
  const float* male_fc_b = (const float*)d_in[22];
  const float* gn_g = (const float*)d_in[23];
  const float* gn_b = (const float*)d_in[24];
  const float* head_w = (const float*)d_in[25];
  const float* head_b = (const float*)d_in[26];
  float* out = (float*)d_out;

  // ws layout (bytes): total 121,929,728 B = 116.3 MiB
  char* w = (char*)d_ws;
  bf16* seq = (bf16*)(w);                    //  16,777,216 B (8M bf16)
  bf16* xz = (bf16*)(w + 16777216);          //  67,108,864 B (33.5M bf16)
  bf16* xc = (bf16*)(w + 83886080);          //  33,554,432 B (16.7M bf16; also hbuf)
  float* xdb = (float*)(w + 117440512);      //   4,194,304 B (1M fp32)
  float* part = (float*)(w + 121634816);     //     262,144 B
  float* pooled = (float*)(w + 121896960);   //      16,384 B
  float* featp = (float*)(w + 121913344);    //      16,384 B

  k_embed<<<B_ * S_, 256, 0, stream>>>(ids, gate, word_emb, pos_emb2, pe, emb_ln_g,
                                       emb_ln_b, seq);

  const int M = B_ * S_;  // 16384
  for (int l = 0; l < NL_; l++) {
    const float* Wi = in_proj_w + (long)l * 2 * DI_ * H_;
    const float* cw = conv_w + (long)l * DI_ * DC_;
    const float* cb = conv_b + (long)l * DI_;
    const float* Wx = x_proj_w + (long)l * (DR_ + 2 * DS_) * DI_;
    const float* Wdt = dt_proj_w + (long)l * DI_ * DR_;
    const float* bdt = dt_proj_b + (long)l * DI_;
    const float* Al = A_log + (long)l * DI_ * DS_;
    const float* Dl = D_param + (long)l * DI_;
    const float* Wo = out_proj_w + (long)l * H_ * DI_;
    const float* bg = blk_ln_g + (long)l * H_;
    const float* bb = blk_ln_b + (long)l * H_;

    // xz = seq @ Wi^T : (16384,512) x (2048,512)^T -> bf16
    k_gemm<0, 128, bf16, bf16><<<dim3(16, 128), 256, 0, stream>>>(
        seq, H_, Wi, H_, nullptr, xz, 2048, H_);
    // conv + silu -> xc (bf16)
    k_conv<<<(B_ * S_ * DI_) / 256, 256, 0, stream>>>(xz, cw, cb, xc);
    // xdb = xc @ Wx^T : (16384,1024) x (64,1024)^T -> fp32
    k_gemm<0, 64, bf16, float><<<dim3(1, 256), 256, 0, stream>>>(
        xc, DI_, Wx, DI_, nullptr, xdb, 64, DI_);
    // dt = softplus(xdb[:,:32] @ Wdt^T + bdt) -> fp16 over dead x-half of xz
    k_gemm<1, 64, float, __half><<<dim3(16, 256), 256, 0, stream>>>(
        xdb, 64, Wdt, DR_, bdt, (__half*)xz, 2048, DR_);
    // selective scan + D skip + z-gate; y (bf16) written over dt in x-half
    k_scan<<<256, 64, 0, stream>>>(xz, xc, xdb, Al, Dl);
    // h = y @ Wo^T : (16384,1024 stride 2048) x (512,1024)^T -> hbuf (= xc region)
    k_gemm<0, 128, bf16, bf16><<<dim3(4, 128), 256, 0, stream>>>(
        xz, 2048, Wo, DI_, nullptr, xc, H_, DI_);
    // seq = gate * LN(h + seq)
    k_resid_ln<<<B_ * S_, 256, 0, stream>>>(xc, gate, bg, bb, seq);
  }

  k_pool1<<<B_ * 16, 512, 0, stream>>>(seq, gate, part);
  k_pool2<<<16, 256, 0, stream>>>(part, pooled);
  k_feat<<<B_, 512, 0, stream>>>(pooled, dense2_w, dense2_b, featp);
  k_head<<<B_, 512, 0, stream>>>(featp, age_sex, male_fc_w, male_fc_b, gn_g, gn_b,
                                 head_w, head_b, out);
  k_copy<<<(B_ * S_ + 255) / 256, 256, 0, stream>>>(gate, out + 16, B_ * S_);
}

// Round 3
// 8302.771 us; speedup vs baseline: 3.5852x; 3.5852x over previous
//
// Round 3: MFMA bf16 GEMMs replace spilling fp32 vector GEMMs.
// R2 post-mortem: fp32 k_gemm had VGPR_Count=64 (acc alone needs 64) -> scratch
// spill -> 5.4 GB WRITE_SIZE per dispatch (84x the 64 MB output), 1.83 ms each.
// Fix: 16x16x32 bf16 MFMA GEMM (m97-style): 128x128 tile, 64x64/wave, 4x4 frags,
// global_load_lds width=16 staging, XOR k-chunk swizzle (8-way -> 4-way LDS).
// Weights converted fp32->bf16 per layer into ws (3.3 MB). dt stays fp16; B/C fp32.
#include <hip/hip_runtime.h>
#include <hip/hip_bf16.h>
#include <hip/hip_fp16.h>
#include <math.h>

#define B_ 8
#define S_ 2048
#define H_ 512
#define DI_ 1024
#define DS_ 16
#define DC_ 4
#define DR_ 32
#define NL_ 8

typedef __hip_bfloat16 bf16;
typedef short bf16x8 __attribute__((ext_vector_type(8)));
typedef float f32x4 __attribute__((ext_vector_type(4)));

static __device__ __forceinline__ float wred_sum(float v) {
#pragma unroll
  for (int o = 32; o; o >>= 1) v += __shfl_down(v, o, 64);
  return v;
}
static __device__ __forceinline__ float bf2f(unsigned short u) {
  return __uint_as_float(((unsigned)u) << 16);
}
static __device__ __forceinline__ void st1(float* p, float v) { *p = v; }
static __device__ __forceinline__ void st1(bf16* p, float v) { *p = __float2bfloat16(v); }
static __device__ __forceinline__ void st1(__half* p, float v) { *p = __float2half(v); }

static __device__ __forceinline__ void gl_lds16(const unsigned short* g,
                                                unsigned short* l) {
  __builtin_amdgcn_global_load_lds(
      (const __attribute__((address_space(1))) void*)g,
      (__attribute__((address_space(3))) void*)l, 16, 0, 0);
}

// ---------------- MFMA GEMM: C[M,N] = X[M,K](bf16) @ W[N,K](bf16)^T ----------
// ACT 0: plain store (TC). ACT 1: bias+softplus (TC=__half). ACT 2: fp32 store
// + bf16 side-copy of cols<32 into dtbf (row stride 32).
template <int BM, int BN, int ACT, typename TC>
__global__ void __launch_bounds__((BM / 64) * (BN / 64) * 64) k_mfma(
    const unsigned short* __restrict__ X, int lda,
    const unsigned short* __restrict__ W, int ldb,
    const float* __restrict__ bias, TC* __restrict__ C, long ldc, int K,
    unsigned short* __restrict__ dtbf) {
  constexpr int NW = (BM / 64) * (BN / 64);   // waves per block
  constexpr int WN = BN / 64;                 // waves along N
  constexpr int SEGS = (BM + BN) / 16;        // 16-row staging segments
  __shared__ unsigned short As[BM * 32];
  __shared__ unsigned short Bs[BN * 32];
  int tid = threadIdx.x;
  int wave = tid >> 6, lane = tid & 63;
  int wm = wave / WN, wn = wave % WN;
  long row0 = (long)blockIdx.y * BM;
  long col0 = (long)blockIdx.x * BN;
  // staging: lane l covers row (l>>2) of a 16-row segment; fetches k-chunk
  // ((l&3) ^ ((l>>2)&3)) so LDS slot (l&3) of row r holds chunk ((l&3)^(r&3)).
  int srow = lane >> 2;
  int kchunk = (lane & 3) ^ (srow & 3);
  f32x4 acc[4][4] = {};
  for (int k0 = 0; k0 < K; k0 += 32) {
#pragma unroll
    for (int s = wave; s < SEGS; s += NW) {
      if (s < BM / 16) {
        const unsigned short* g =
            X + (row0 + s * 16 + srow) * (long)lda + k0 + kchunk * 8;
        gl_lds16(g, &As[s * 16 * 32]);
      } else {
        int s2 = s - BM / 16;
        const unsigned short* g =
            W + (col0 + s2 * 16 + srow) * (long)ldb + k0 + kchunk * 8;
        gl_lds16(g, &Bs[s2 * 16 * 32]);
      }
    }
    __syncthreads();
    int fr = lane & 15;                       // fragment row within 16
    int slot = (lane >> 4) ^ (lane & 3);      // swizzled k-chunk slot
    bf16x8 af[4], bfr[4];
#pragma unroll
    for (int i = 0; i < 4; i++)
      af[i] = *(const bf16x8*)&As[(wm * 64 + i * 16 + fr) * 32 + slot * 8];
#pragma unroll
    for (int j = 0; j < 4; j++)
      bfr[j] = *(const bf16x8*)&Bs[(wn * 64 + j * 16 + fr) * 32 + slot * 8];
#pragma unroll
    for (int i = 0; i < 4; i++)
#pragma unroll
      for (int j = 0; j < 4; j++)
        acc[i][j] = __builtin_amdgcn_mfma_f32_16x16x32_bf16(af[i], bfr[j],
                                                            acc[i][j], 0, 0, 0);
    __syncthreads();
  }
  // epilogue: C/D layout col=lane&15, row=(lane>>4)*4+reg
#pragma unroll
  for (int i = 0; i < 4; i++) {
#pragma unroll
    for (int j = 0; j < 4; j++) {
      long rbase = row0 + wm * 64 + i * 16 + ((lane >> 4) << 2);
      long c = col0 + wn * 64 + j * 16 + (lane & 15);
#pragma unroll
      for (int reg = 0; reg < 4; reg++) {
        float v = acc[i][j][reg];
        long r = rbase + reg;
        if constexpr (ACT == 1) {
          v += bias[c];
          v = fmaxf(v, 0.f) + log1pf(__expf(-fabsf(v)));  // softplus
        }
        st1(&C[r * ldc + c], v);
        if constexpr (ACT == 2) {
          if (c < 32) st1((bf16*)&dtbf[r * 32 + c], v);
        }
      }
    }
  }
}

// ---------------- weight fp32 -> bf16 conversion (4 regions, one launch) -----
__global__ void k_convert4(const float* __restrict__ s0, int n0,
                           const float* __restrict__ s1, int n1,
                           const float* __restrict__ s2, int n2,
                           const float* __restrict__ s3, int n3,
                           bf16* __restrict__ d0, bf16* __restrict__ d1,
                           bf16* __restrict__ d2, bf16* __restrict__ d3) {
  int i = blockIdx.x * 256 + threadIdx.x;  // float4 index
  int t0 = n0 >> 2, t1 = t0 + (n1 >> 2), t2 = t1 + (n2 >> 2), t3 = t2 + (n3 >> 2);
  const float* s;
  bf16* d;
  int loc;
  if (i < t0) { s = s0; d = d0; loc = i; }
  else if (i < t1) { s = s1; d = d1; loc = i - t0; }
  else if (i < t2) { s = s2; d = d2; loc = i - t1; }
  else if (i < t3) { s = s3; d = d3; loc = i - t2; }
  else return;
  float4 v = ((const float4*)s)[loc];
  bf16* o = d + (long)loc * 4;
  st1(o + 0, v.x); st1(o + 1, v.y); st1(o + 2, v.z); st1(o + 3, v.w);
}

// ---------------- K1: embedding + LN + gate ----------------
__global__ void k_embed(const int* __restrict__ ids, const float* __restrict__ gate,
                        const float* __restrict__ wemb, const float* __restrict__ pos2,
                        const float* __restrict__ pe, const float* __restrict__ g,
                        const float* __restrict__ bta, bf16* __restrict__ seq) {
  int row = blockIdx.x;
  int s = row % S_;
  int t = threadIdx.x;  // 256
  int id = ids[row];
  float v[2];
#pragma unroll
  for (int i = 0; i < 2; i++) {
    int h = t + i * 256;
    v[i] = pos2[s * H_ + h] * wemb[(long)id * H_ + h] + pe[s * H_ + h];
  }
  float lsum = v[0] + v[1];
  float lsq = v[0] * v[0] + v[1] * v[1];
  __shared__ float smA[4], smB[4];
  int lane = t & 63, w = t >> 6;
  lsum = wred_sum(lsum);
  lsq = wred_sum(lsq);
  if (!lane) { smA[w] = lsum; smB[w] = lsq; }
  __syncthreads();
  float tot = smA[0] + smA[1] + smA[2] + smA[3];
  float totq = smB[0] + smB[1] + smB[2] + smB[3];
  float mu = tot * (1.f / H_);
  float var = totq * (1.f / H_) - mu * mu;
  float inv = rsqrtf(fmaxf(var, 0.f) + 1e-12f);
  float gt = gate[row];
#pragma unroll
  for (int i = 0; i < 2; i++) {
    int h = t + i * 256;
    st1(&seq[(long)row * H_ + h], gt * (g[h] * (v[i] - mu) * inv + bta[h]));
  }
}

// ---------------- conv (depthwise causal, DC=4) + silu ----------------
__global__ void k_conv(const bf16* __restrict__ xz, const float* __restrict__ cw,
                       const float* __restrict__ cb, bf16* __restrict__ xc) {
  long idx = (long)blockIdx.x * 256 + threadIdx.x;  // < B*S*DI
  int d = (int)(idx & 1023);
  long bt = idx >> 10;
  int t = (int)(bt & 2047);
  const unsigned short* xbase = (const unsigned short*)xz + (bt - t) * 2048 + d;
  float acc = cb[d];
#pragma unroll
  for (int k = 0; k < 4; k++) {
    int ts = t + k - 3;
    if (ts >= 0) acc += cw[d * 4 + k] * bf2f(xbase[(long)ts * 2048]);
  }
  float s = acc / (1.f + __expf(-acc));  // silu
  st1(&xc[idx], s);
}

// ---------------- selective scan: 2 lanes per (b,d), 8 states each ----------
__global__ void __launch_bounds__(64) k_scan(
    bf16* __restrict__ xzb, const bf16* __restrict__ xc,
    const float* __restrict__ xdb, const float* __restrict__ Alog,
    const float* __restrict__ Dp) {
  int idx = blockIdx.x * 64 + threadIdx.x;  // 0..16383
  int half = idx & 1;
  int p = idx >> 1;
  int d = p & 1023;
  int b = p >> 10;
  int n0 = half * 8;
  float A[8];
#pragma unroll
  for (int n = 0; n < 8; n++) A[n] = -__expf(Alog[d * 16 + n0 + n]);
  float Dd = Dp[d];
  float h[8] = {0, 0, 0, 0, 0, 0, 0, 0};
  const __half* dtb = (const __half*)xzb + (long)b * S_ * 2048 + d;
  const unsigned short* xb = (const unsigned short*)xc + (long)b * S_ * DI_ + d;
  const unsigned short* zb = (const unsigned short*)xzb + (long)b * S_ * 2048 + DI_ + d;
  const float* bcb = xdb + (long)b * S_ * 64 + DR_ + n0;
  bf16* yb = xzb + (long)b * S_ * 2048 + d;
  float dt_c = __half2float(dtb[0]);
  float x_c = bf2f(xb[0]);
  float z_c = bf2f(zb[0]);
  float Bc[8], Cc[8];
#pragma unroll
  for (int n = 0; n < 8; n++) { Bc[n] = bcb[n]; Cc[n] = bcb[16 + n]; }
  for (int t = 0; t < S_; t++) {
    float dt_n = 0.f, x_n = 0.f, z_n = 0.f, Bn[8], Cn[8];
#pragma unroll
    for (int n = 0; n < 8; n++) { Bn[n] = 0.f; Cn[n] = 0.f; }
    if (t + 1 < S_) {
      long o = (long)(t + 1);
      dt_n = __half2float(dtb[o * 2048]);
      x_n = bf2f(xb[o * DI_]);
      z_n = bf2f(zb[o * 2048]);
      const float* bc = bcb + o * 64;
#pragma unroll
      for (int n = 0; n < 8; n++) { Bn[n] = bc[n]; Cn[n] = bc[16 + n]; }
    }
    float dx = dt_c * x_c;
    float yacc = 0.f;
#pragma unroll
    for (int n = 0; n < 8; n++) {
      float hn = __expf(dt_c * A[n]) * h[n] + dx * Bc[n];
      h[n] = hn;
      yacc += hn * Cc[n];
    }
    yacc += __shfl_xor(yacc, 1, 64);
    if (!half) {
      float sz = z_c / (1.f + __expf(-z_c));
      st1(&yb[(long)t * 2048], (yacc + Dd * x_c) * sz);
    }
    dt_c = dt_n; x_c = x_n; z_c = z_n;
#pragma unroll
    for (int n = 0; n < 8; n++) { Bc[n] = Bn[n]; Cc[n] = Cn[n]; }
  }
}

// ---------------- residual + LN + gate (in-place on seq) ----------------
__global__ void k_resid_ln(const bf16* __restrict__ hb, const float* __restrict__ gate,
                           const float* __restrict__ g, const float* __restrict__ bta,
                           bf16* __restrict__ seq) {
  int row = blockIdx.x;
  int t = threadIdx.x;  // 256
  float v[2];
#pragma unroll
  for (int i = 0; i < 2; i++) {
    int h = t + i * 256;
    v[i] = bf2f(((const unsigned short*)hb)[(long)row * H_ + h]) +
           bf2f(((const unsigned short*)seq)[(long)row * H_ + h]);
  }
  float lsum = v[0] + v[1];
  float lsq = v[0] * v[0] + v[1] * v[1];
  __shared__ float smA[4], smB[4];
  int lane = t & 63, w = t >> 6;
  lsum = wred_sum(lsum);
  lsq = wred_sum(lsq);
  if (!lane) { smA[w] = lsum; smB[w] = lsq; }
  __syncthreads();
  float tot = smA[0] + smA[1] + smA[2] + smA[3];
  float totq = smB[0] + smB[1] + smB[2] + smB[3];
  float mu = tot * (1.f / H_);
  float var = totq * (1.f / H_) - mu * mu;
  float inv = rsqrtf(fmaxf(var, 0.f) + 1e-12f);
  float gt = gate[row];
#pragma unroll
  for (int i = 0; i < 2; i++) {
    int h = t + i * 256;
    st1(&seq[(long)row * H_ + h], gt * (g[h] * (v[i] - mu) * inv + bta[h]));
  }
}

// ---------------- max pool (two stage) ----------------
__global__ void k_pool1(const bf16* __restrict__ seq, const float* __restrict__ gate,
                        float* __restrict__ part) {
  int blk = blockIdx.x;  // B*16
  int b = blk >> 4, c = blk & 15;
  int h = threadIdx.x;   // 512
  float m = -3.4e38f;
  for (int i = 0; i < 128; i++) {
    long r = (long)b * S_ + c * 128 + i;
    m = fmaxf(m, bf2f(((const unsigned short*)seq)[r * H_ + h]) * gate[r]);
  }
  part[((long)b * 16 + c) * H_ + h] = m;
}
__global__ void k_pool2(const float* __restrict__ part, float* __restrict__ pooled) {
  int idx = blockIdx.x * 256 + threadIdx.x;  // 4096
  int b = idx >> 9, h = idx & 511;
  float m = -3.4e38f;
#pragma unroll
  for (int c = 0; c < 16; c++) m = fmaxf(m, part[((long)b * 16 + c) * H_ + h]);
  pooled[idx] = m;
}

// ---------------- dense2 + gelu_new ----------------
__global__ void k_feat(const float* __restrict__ pooled, const float* __restrict__ W2,
                       const float* __restrict__ b2, float* __restrict__ feat) {
  int b = blockIdx.x;
  int j = threadIdx.x;  // 512
  __shared__ float ps[512];
  ps[j] = pooled[b * 512 + j];
  __syncthreads();
  float acc = b2[j];
  const float* wr = W2 + (long)j * 512;
  for (int k = 0; k < 512; k++) acc += ps[k] * wr[k];
  float x = acc;
  float u = 0.7978845608028654f * (x + 0.044715f * x * x * x);
  feat[b * 512 + j] = 0.5f * x * (1.f + tanhf(u));
}

// ---------------- GroupNorm + FiLM(style) + head ----------------
__global__ void k_head(const float* __restrict__ feat, const float* __restrict__ age_sex,
                       const float* __restrict__ mw, const float* __restrict__ mb,
                       const float* __restrict__ gng, const float* __restrict__ gnb,
                       const float* __restrict__ hw, const float* __restrict__ hb,
                       float* __restrict__ out) {
  int b = blockIdx.x;
  int j = threadIdx.x;  // 512
  float f = feat[b * 512 + j];
  __shared__ float sA[8], sB[8];
  int lane = j & 63, w = j >> 6;
  float s1 = wred_sum(f);
  float s2 = wred_sum(f * f);
  if (!lane) { sA[w] = s1; sB[w] = s2; }
  __syncthreads();
  int g = j >> 7;
  float tot = sA[2 * g] + sA[2 * g + 1];
  float totq = sB[2 * g] + sB[2 * g + 1];
  float mu = tot * (1.f / 128.f);
  float var = totq * (1.f / 128.f) - mu * mu;
  float gn = (f - mu) * rsqrtf(fmaxf(var, 0.f) + 1e-5f) * gng[j] + gnb[j];
  float a0 = age_sex[b * 2], a1 = age_sex[b * 2 + 1];
  float sa = a0 * mw[j * 2] + a1 * mw[j * 2 + 1] + mb[j];
  sa = sa > 0.f ? sa : (__expf(sa) - 1.f);
  int j2 = 512 + j;
  float sb = a0 * mw[j2 * 2] + a1 * mw[j2 * 2 + 1] + mb[j2];
  sb = sb > 0.f ? sb : (__expf(sb) - 1.f);
  float feature = (1.f + sa) * gn + sb;
  out[16 + 16384 + b * 512 + j] = feature;
  float l0 = feature * hw[j];
  float l1 = feature * hw[512 + j];
  __syncthreads();
  l0 = wred_sum(l0);
  l1 = wred_sum(l1);
  if (!lane) { sA[w] = l0; sB[w] = l1; }
  __syncthreads();
  if (j == 0) {
    float t0 = 0.f, t1 = 0.f;
#pragma unroll
    for (int i = 0; i < 8; i++) { t0 += sA[i]; t1 += sB[i]; }
    out[b * 2 + 0] = t0 + hb[0];
    out[b * 2 + 1] = t1 + hb[1];
  }
}

__global__ void k_copy(const float* __restrict__ src, float* __restrict__ dst, int n) {
  int i = blockIdx.x * 256 + threadIdx.x;
  if (i < n) dst[i] = src[i];
}

// ---------------- launch ----------------
extern "C" void kernel_launch(void* const* d_in, const int* in_sizes, int n_in,
                              void* d_out, int out_size, void* d_ws, size_t ws_size,
                              hipStream_t stream) {
  const int* ids = (const int*)d_in[0];
  const float* gate = (const float*)d_in[1];
  const float* age_sex = (const float*)d_in[2];
  const float* word_emb = (const float*)d_in[3];
  const float* pos_emb2 = (const float*)d_in[4];
  const float* pe = (const float*)d_in[5];
  const float* emb_ln_g = (const float*)d_in[6];
  const float* emb_ln_b = (const float*)d_in[7];
  const float* in_proj_w = (const float*)d_in[8];
  const float* conv_w = (const float*)d_in[9];
  const float* conv_b = (const float*)d_in[10];
  const float* x_proj_w = (const float*)d_in[11];
  const float* dt_proj_w = (const float*)d_in[12];
  const float* dt_proj_b = (const float*)d_in[13];
  const float* A_log = (const float*)d_in[14];
  const float* D_param = (const float*)d_in[15];
  const float* out_proj_w = (const float*)d_in[16];
  const float* blk_ln_g = (const float*)d_in[17];
  const float* blk_ln_b = (const float*)d_in[18];
  const float* dense2_w = (const float*)d_in[19];
  const float* dense2_b = (const float*)d_in[20];
  const float* male_fc_w = (const float*)d_in[21];
  const float* male_fc_b = (const float*)d_in[22];
  const float* gn_g = (const float*)d_in[23];
  const float* gn_b = (const float*)d_in[24];
  const float* head_w = (const float*)d_in[25];
  const float* head_b = (const float*)d_in[26];
  float* out = (float*)d_out;

  // ws layout (bytes), total 126,320,640 B = 120.5 MiB
  char* w = (char*)d_ws;
  bf16* seq = (bf16*)(w);                      //  16,777,216
  bf16* xz = (bf16*)(w + 16777216);            //  67,108,864
  bf16* xc = (bf16*)(w + 83886080);            //  33,554,432 (also hbuf)
  float* xdb = (float*)(w + 117440512);        //   4,194,304
  bf16* xdt = (bf16*)(w + 121634816);          //   1,048,576 (16384x32 bf16)
  bf16* wi_b = (bf16*)(w + 122683392);         //   2,097,152 (2048x512)
  bf16* wx_b = (bf16*)(w + 124780544);         //     131,072 (64x1024)
  bf16* wdt_b = (bf16*)(w + 124911616);        //      65,536 (1024x32)
  bf16* wo_b = (bf16*)(w + 124977152);         //   1,048,576 (512x1024)
  float* part = (float*)(w + 126025728);       //     262,144
  float* pooled = (float*)(w + 126287872);     //      16,384
  float* featp = (float*)(w + 126304256);      //      16,384

  k_embed<<<B_ * S_, 256, 0, stream>>>(ids, gate, word_emb, pos_emb2, pe, emb_ln_g,
                                       emb_ln_b, seq);

  const int nWi = 2 * DI_ * H_;      // 1,048,576
  const int nWx = 64 * DI_;          // 65,536
  const int nWdt = DI_ * DR_;        // 32,768
  const int nWo = H_ * DI_;          // 524,288
  const int cvt_blocks = (nWi + nWx + nWdt + nWo) / 4 / 256;  // 1632

  for (int l = 0; l < NL_; l++) {
    const float* Wi = in_proj_w + (long)l * nWi;
    const float* cw = conv_w + (long)l * DI_ * DC_;
    const float* cb = conv_b + (long)l * DI_;
    const float* Wx = x_proj_w + (long)l * nWx;
    const float* Wdt = dt_proj_w + (long)l * nWdt;
    const float* bdt = dt_proj_b + (long)l * DI_;
    const float* Al = A_log + (long)l * DI_ * DS_;
    const float* Dl = D_param + (long)l * DI_;
    const float* Wo = out_proj_w + (long)l * nWo;
    const float* bg = blk_ln_g + (long)l * H_;
    const float* bb = blk_ln_b + (long)l * H_;

    k_convert4<<<cvt_blocks, 256, 0, stream>>>(Wi, nWi, Wx, nWx, Wdt, nWdt, Wo, nWo,
                                               wi_b, wx_b, wdt_b, wo_b);

    // xz = seq @ Wi^T : (16384,512)x(2048,512)^T -> bf16, ldc 2048
    k_mfma<128, 128, 0, bf16><<<dim3(16, 128), 256, 0, stream>>>(
        (const unsigned short*)seq, H_, (const unsigned short*)wi_b, H_, nullptr,
        xz, 2048, H_, nullptr);
    // conv + silu -> xc
    k_conv<<<(B_ * S_ * DI_) / 256, 256, 0, stream>>>(xz, cw, cb, xc);
    // xdb = xc @ Wx^T : (16384,1024)x(64,1024)^T -> fp32 + bf16 cols<32 -> xdt
    k_mfma<128, 64, 2, float><<<dim3(1, 128), 128, 0, stream>>>(
        (const unsigned short*)xc, DI_, (const unsigned short*)wx_b, DI_, nullptr,
        xdb, 64, DI_, (unsigned short*)xdt);
    // dt = softplus(xdt @ Wdt^T + bdt) : (16384,32)x(1024,32)^T -> fp16 in xz x-half
    k_mfma<128, 128, 1, __half><<<dim3(8, 128), 256, 0, stream>>>(
        (const unsigned short*)xdt, 32, (const unsigned short*)wdt_b, DR_, bdt,
        (__half*)xz, 2048, DR_, nullptr);
    // selective scan; y (bf16) written over dt in xz x-half
    k_scan<<<256, 64, 0, stream>>>(xz, xc, xdb, Al, Dl);
    // h = y @ Wo^T : (16384,1024 stride2048)x(512,1024)^T -> bf16 hbuf (=xc)
    k_mfma<128, 128, 0, bf16><<<dim3(4, 128), 256, 0, stream>>>(
        (const unsigned short*)xz, 2048, (const unsigned short*)wo_b, DI_, nullptr,
        xc, H_, DI_, nullptr);
    // seq = gate * LN(h + seq)
    k_resid_ln<<<B_ * S_, 256, 0, stream>>>(xc, gate, bg, bb, seq);
  }

  k_pool1<<<B_ * 16, 512, 0, stream>>>(seq, gate, part);
  k_pool2<<<16, 256, 0, stream>>>(part, pooled);
  k_feat<<<B_, 512, 0, stream>>>(pooled, dense2_w, dense2_b, featp);
  k_head<<<B_, 512, 0, stream>>>(featp, age_sex, male_fc_w, male_fc_b, gn_g, gn_b,
                                 head_w, head_b, out);
  k_copy<<<(B_ * S_ + 255) / 256, 256, 0, stream>>>(gate, out + 16, B_ * S_);
}

// Round 4
// 3726.547 us; speedup vs baseline: 7.9878x; 2.2280x over previous
//
// Round 4: chunked parallel selective scan.
// R3 post-mortem: k_scan = 75% of runtime; 770us/2048 steps = ~900cyc/step =
// one HBM latency per step at 1 wave/CU (Occupancy 2.9%) -- latency-bound.
// Fix: 2-pass chunked scan (NC=8 x LC=256). Chunk transition = exp(A*sum_dt)
// (scalar per (b,d,chunk)) so phase A stores only h_final (4MB) + sum_dt
// (256KB). Phase C combines <=7 chunk summaries in-registers then rescans its
// chunk with depth-4 prefetch. 8 waves/CU + 4-deep pipeline vs 1 wave/CU +
// 1-deep. ws +4.45MB -> 130.8MB; fallback to serial scan if ws_size too small.
#include <hip/hip_runtime.h>
#include <hip/hip_bf16.h>
#include <hip/hip_fp16.h>
#include <math.h>

#define B_ 8
#define S_ 2048
#define H_ 512
#define DI_ 1024
#define DS_ 16
#define DC_ 4
#define DR_ 32
#define NL_ 8
#define NC_ 8
#define LC_ (S_ / NC_)  // 256
#define PF_ 4

typedef __hip_bfloat16 bf16;
typedef short bf16x8 __attribute__((ext_vector_type(8)));
typedef float f32x4 __attribute__((ext_vector_type(4)));

static __device__ __forceinline__ float wred_sum(float v) {
#pragma unroll
  for (int o = 32; o; o >>= 1) v += __shfl_down(v, o, 64);
  return v;
}
static __device__ __forceinline__ float bf2f(unsigned short u) {
  return __uint_as_float(((unsigned)u) << 16);
}
static __device__ __forceinline__ void st1(float* p, float v) { *p = v; }
static __device__ __forceinline__ void st1(bf16* p, float v) { *p = __float2bfloat16(v); }
static __device__ __forceinline__ void st1(__half* p, float v) { *p = __float2half(v); }

static __device__ __forceinline__ void gl_lds16(const unsigned short* g,
                                                unsigned short* l) {
  __builtin_amdgcn_global_load_lds(
      (const __attribute__((address_space(1))) void*)g,
      (__attribute__((address_space(3))) void*)l, 16, 0, 0);
}

// ---------------- MFMA GEMM: C[M,N] = X[M,K](bf16) @ W[N,K](bf16)^T ----------
template <int BM, int BN, int ACT, typename TC>
__global__ void __launch_bounds__((BM / 64) * (BN / 64) * 64) k_mfma(
    const unsigned short* __restrict__ X, int lda,
    const unsigned short* __restrict__ W, int ldb,
    const float* __restrict__ bias, TC* __restrict__ C, long ldc, int K,
    unsigned short* __restrict__ dtbf) {
  constexpr int NW = (BM / 64) * (BN / 64);
  constexpr int WN = BN / 64;
  constexpr int SEGS = (BM + BN) / 16;
  __shared__ unsigned short As[BM * 32];
  __shared__ unsigned short Bs[BN * 32];
  int tid = threadIdx.x;
  int wave = tid >> 6, lane = tid & 63;
  int wm = wave / WN, wn = wave % WN;
  long row0 = (long)blockIdx.y * BM;
  long col0 = (long)blockIdx.x * BN;
  int srow = lane >> 2;
  int kchunk = (lane & 3) ^ (srow & 3);
  f32x4 acc[4][4] = {};
  for (int k0 = 0; k0 < K; k0 += 32) {
#pragma unroll
    for (int s = wave; s < SEGS; s += NW) {
      if (s < BM / 16) {
        const unsigned short* g =
            X + (row0 + s * 16 + srow) * (long)lda + k0 + kchunk * 8;
        gl_lds16(g, &As[s * 16 * 32]);
      } else {
        int s2 = s - BM / 16;
        const unsigned short* g =
            W + (col0 + s2 * 16 + srow) * (long)ldb + k0 + kchunk * 8;
        gl_lds16(g, &Bs[s2 * 16 * 32]);
      }
    }
    __syncthreads();
    int fr = lane & 15;
    int slot = (lane >> 4) ^ (lane & 3);
    bf16x8 af[4], bfr[4];
#pragma unroll
    for (int i = 0; i < 4; i++)
      af[i] = *(const bf16x8*)&As[(wm * 64 + i * 16 + fr) * 32 + slot * 8];
#pragma unroll
    for (int j = 0; j < 4; j++)
      bfr[j] = *(const bf16x8*)&Bs[(wn * 64 + j * 16 + fr) * 32 + slot * 8];
#pragma unroll
    for (int i = 0; i < 4; i++)
#pragma unroll
      for (int j = 0; j < 4; j++)
        acc[i][j] = __builtin_amdgcn_mfma_f32_16x16x32_bf16(af[i], bfr[j],
                                                            acc[i][j], 0, 0, 0);
    __syncthreads();
  }
#pragma unroll
  for (int i = 0; i < 4; i++) {
#pragma unroll
    for (int j = 0; j < 4; j++) {
      long rbase = row0 + wm * 64 + i * 16 + ((lane >> 4) << 2);
      long c = col0 + wn * 64 + j * 16 + (lane & 15);
#pragma unroll
      for (int reg = 0; reg < 4; reg++) {
        float v = acc[i][j][reg];
        long r = rbase + reg;
        if constexpr (ACT == 1) {
          v += bias[c];
          v = fmaxf(v, 0.f) + log1pf(__expf(-fabsf(v)));  // softplus
        }
        st1(&C[r * ldc + c], v);
        if constexpr (ACT == 2) {
          if (c < 32) st1((bf16*)&dtbf[r * 32 + c], v);
        }
      }
    }
  }
}

// ---------------- weight fp32 -> bf16 conversion ----------------
__global__ void k_convert4(const float* __restrict__ s0, int n0,
                           const float* __restrict__ s1, int n1,
                           const float* __restrict__ s2, int n2,
                           const float* __restrict__ s3, int n3,
                           bf16* __restrict__ d0, bf16* __restrict__ d1,
                           bf16* __restrict__ d2, bf16* __restrict__ d3) {
  int i = blockIdx.x * 256 + threadIdx.x;
  int t0 = n0 >> 2, t1 = t0 + (n1 >> 2), t2 = t1 + (n2 >> 2), t3 = t2 + (n3 >> 2);
  const float* s;
  bf16* d;
  int loc;
  if (i < t0) { s = s0; d = d0; loc = i; }
  else if (i < t1) { s = s1; d = d1; loc = i - t0; }
  else if (i < t2) { s = s2; d = d2; loc = i - t1; }
  else if (i < t3) { s = s3; d = d3; loc = i - t2; }
  else return;
  float4 v = ((const float4*)s)[loc];
  bf16* o = d + (long)loc * 4;
  st1(o + 0, v.x); st1(o + 1, v.y); st1(o + 2, v.z); st1(o + 3, v.w);
}

// ---------------- K1: embedding + LN + gate ----------------
__global__ void k_embed(const int* __restrict__ ids, const float* __restrict__ gate,
                        const float* __restrict__ wemb, const float* __restrict__ pos2,
                        const float* __restrict__ pe, const float* __restrict__ g,
                        const float* __restrict__ bta, bf16* __restrict__ seq) {
  int row = blockIdx.x;
  int s = row % S_;
  int t = threadIdx.x;
  int id = ids[row];
  float v[2];
#pragma unroll
  for (int i = 0; i < 2; i++) {
    int h = t + i * 256;
    v[i] = pos2[s * H_ + h] * wemb[(long)id * H_ + h] + pe[s * H_ + h];
  }
  float lsum = v[0] + v[1];
  float lsq = v[0] * v[0] + v[1] * v[1];
  __shared__ float smA[4], smB[4];
  int lane = t & 63, w = t >> 6;
  lsum = wred_sum(lsum);
  lsq = wred_sum(lsq);
  if (!lane) { smA[w] = lsum; smB[w] = lsq; }
  __syncthreads();
  float tot = smA[0] + smA[1] + smA[2] + smA[3];
  float totq = smB[0] + smB[1] + smB[2] + smB[3];
  float mu = tot * (1.f / H_);
  float var = totq * (1.f / H_) - mu * mu;
  float inv = rsqrtf(fmaxf(var, 0.f) + 1e-12f);
  float gt = gate[row];
#pragma unroll
  for (int i = 0; i < 2; i++) {
    int h = t + i * 256;
    st1(&seq[(long)row * H_ + h], gt * (g[h] * (v[i] - mu) * inv + bta[h]));
  }
}

// ---------------- conv (depthwise causal, DC=4) + silu ----------------
__global__ void k_conv(const bf16* __restrict__ xz, const float* __restrict__ cw,
                       const float* __restrict__ cb, bf16* __restrict__ xc) {
  long idx = (long)blockIdx.x * 256 + threadIdx.x;
  int d = (int)(idx & 1023);
  long bt = idx >> 10;
  int t = (int)(bt & 2047);
  const unsigned short* xbase = (const unsigned short*)xz + (bt - t) * 2048 + d;
  float acc = cb[d];
#pragma unroll
  for (int k = 0; k < 4; k++) {
    int ts = t + k - 3;
    if (ts >= 0) acc += cw[d * 4 + k] * bf2f(xbase[(long)ts * 2048]);
  }
  float s = acc / (1.f + __expf(-acc));
  st1(&xc[idx], s);
}

// ---------------- serial scan (fallback when ws too small) ----------------
__global__ void __launch_bounds__(64) k_scan(
    bf16* __restrict__ xzb, const bf16* __restrict__ xc,
    const float* __restrict__ xdb, const float* __restrict__ Alog,
    const float* __restrict__ Dp) {
  int idx = blockIdx.x * 64 + threadIdx.x;
  int half = idx & 1;
  int p = idx >> 1;
  int d = p & 1023;
  int b = p >> 10;
  int n0 = half * 8;
  float A[8];
#pragma unroll
  for (int n = 0; n < 8; n++) A[n] = -__expf(Alog[d * 16 + n0 + n]);
  float Dd = Dp[d];
  float h[8] = {0, 0, 0, 0, 0, 0, 0, 0};
  const __half* dtb = (const __half*)xzb + (long)b * S_ * 2048 + d;
  const unsigned short* xb = (const unsigned short*)xc + (long)b * S_ * DI_ + d;
  const unsigned short* zb = (const unsigned short*)xzb + (long)b * S_ * 2048 + DI_ + d;
  const float* bcb = xdb + (long)b * S_ * 64 + DR_ + n0;
  bf16* yb = xzb + (long)b * S_ * 2048 + d;
  float dt_c = __half2float(dtb[0]);
  float x_c = bf2f(xb[0]);
  float z_c = bf2f(zb[0]);
  float Bc[8], Cc[8];
#pragma unroll
  for (int n = 0; n < 8; n++) { Bc[n] = bcb[n]; Cc[n] = bcb[16 + n]; }
  for (int t = 0; t < S_; t++) {
    float dt_n = 0.f, x_n = 0.f, z_n = 0.f, Bn[8], Cn[8];
#pragma unroll
    for (int n = 0; n < 8; n++) { Bn[n] = 0.f; Cn[n] = 0.f; }
    if (t + 1 < S_) {
      long o = (long)(t + 1);
      dt_n = __half2float(dtb[o * 2048]);
      x_n = bf2f(xb[o * DI_]);
      z_n = bf2f(zb[o * 2048]);
      const float* bc = bcb + o * 64;
#pragma unroll
      for (int n = 0; n < 8; n++) { Bn[n] = bc[n]; Cn[n] = bc[16 + n]; }
    }
    float dx = dt_c * x_c;
    float yacc = 0.f;
#pragma unroll
    for (int n = 0; n < 8; n++) {
      float hn = __expf(dt_c * A[n]) * h[n] + dx * Bc[n];
      h[n] = hn;
      yacc += hn * Cc[n];
    }
    yacc += __shfl_xor(yacc, 1, 64);
    if (!half) {
      float sz = z_c / (1.f + __expf(-z_c));
      st1(&yb[(long)t * 2048], (yacc + Dd * x_c) * sz);
    }
    dt_c = dt_n; x_c = x_n; z_c = z_n;
#pragma unroll
    for (int n = 0; n < 8; n++) { Bc[n] = Bn[n]; Cc[n] = Cn[n]; }
  }
}

// ---------------- chunked scan phase A: per-chunk h_final + sum_dt ----------
// thread idx: [chunk c | (b,d,half) pf]; grid 2048x64.
__global__ void __launch_bounds__(64) k_scanA(
    const bf16* __restrict__ xzb, const bf16* __restrict__ xc,
    const float* __restrict__ xdb, const float* __restrict__ Alog,
    float* __restrict__ hf, float* __restrict__ sdt) {
  int idx = blockIdx.x * 64 + threadIdx.x;  // 0..131071
  int pf = idx & 16383;
  int c = idx >> 14;
  int half = pf & 1;
  int p = pf >> 1;
  int d = p & 1023;
  int b = p >> 10;
  int n0 = half * 8;
  float A[8];
#pragma unroll
  for (int n = 0; n < 8; n++) A[n] = -__expf(Alog[d * 16 + n0 + n]);
  const __half* dtb = (const __half*)xzb + (long)b * S_ * 2048 + d;
  const unsigned short* xb = (const unsigned short*)xc + (long)b * S_ * DI_ + d;
  const float* bcb = xdb + (long)b * S_ * 64 + DR_ + n0;
  int t0 = c * LC_;
  float dtv[PF_], xv[PF_];
  f32x4 Bv0[PF_], Bv1[PF_];
#pragma unroll
  for (int i = 0; i < PF_; i++) {
    long o = t0 + i;
    dtv[i] = __half2float(dtb[o * 2048]);
    xv[i] = bf2f(xb[o * DI_]);
    Bv0[i] = *(const f32x4*)(bcb + o * 64);
    Bv1[i] = *(const f32x4*)(bcb + o * 64 + 4);
  }
  float h[8] = {0, 0, 0, 0, 0, 0, 0, 0};
  float sd = 0.f;
  for (int t = 0; t < LC_; t += PF_) {
#pragma unroll
    for (int u = 0; u < PF_; u++) {
      float dt_c = dtv[u], x_c = xv[u];
      float Bl[8] = {Bv0[u][0], Bv0[u][1], Bv0[u][2], Bv0[u][3],
                     Bv1[u][0], Bv1[u][1], Bv1[u][2], Bv1[u][3]};
      long o = t0 + t + u + PF_;
      if (o > S_ - 1) o = S_ - 1;  // harmless re-read (read-only in phase A)
      dtv[u] = __half2float(dtb[o * 2048]);
      xv[u] = bf2f(xb[o * DI_]);
      Bv0[u] = *(const f32x4*)(bcb + o * 64);
      Bv1[u] = *(const f32x4*)(bcb + o * 64 + 4);
      sd += dt_c;
      float dx = dt_c * x_c;
#pragma unroll
      for (int n = 0; n < 8; n++)
        h[n] = __expf(dt_c * A[n]) * h[n] + dx * Bl[n];
    }
  }
  float* ho = hf + (long)idx * 8;
#pragma unroll
  for (int n = 0; n < 8; n++) ho[n] = h[n];
  if (!half) sdt[c * 8192 + p] = sd;
}

// ---------------- chunked scan phase C: combine starts + rescan with y ------
__global__ void __launch_bounds__(64) k_scanC(
    bf16* __restrict__ xzb, const bf16* __restrict__ xc,
    const float* __restrict__ xdb, const float* __restrict__ Alog,
    const float* __restrict__ Dp, const float* __restrict__ hf,
    const float* __restrict__ sdt) {
  int idx = blockIdx.x * 64 + threadIdx.x;
  int pf = idx & 16383;
  int c = idx >> 14;  // wave-uniform
  int half = pf & 1;
  int p = pf >> 1;
  int d = p & 1023;
  int b = p >> 10;
  int n0 = half * 8;
  float A[8];
#pragma unroll
  for (int n = 0; n < 8; n++) A[n] = -__expf(Alog[d * 16 + n0 + n]);
  float Dd = Dp[d];
  // h_start = fold of preceding chunk summaries (exp(A*sum_dt) == step product)
  float h[8] = {0, 0, 0, 0, 0, 0, 0, 0};
  for (int j = 0; j < c; j++) {
    float sd = sdt[j * 8192 + p];
    const float* hj = hf + ((long)j * 16384 + pf) * 8;
#pragma unroll
    for (int n = 0; n < 8; n++) h[n] = __expf(sd * A[n]) * h[n] + hj[n];
  }
  const __half* dtb = (const __half*)xzb + (long)b * S_ * 2048 + d;
  const unsigned short* xb = (const unsigned short*)xc + (long)b * S_ * DI_ + d;
  const unsigned short* zb = (const unsigned short*)xzb + (long)b * S_ * 2048 + DI_ + d;
  const float* bcb = xdb + (long)b * S_ * 64 + DR_ + n0;
  bf16* yb = xzb + (long)b * S_ * 2048 + d;
  int t0 = c * LC_;
  int tend = t0 + LC_ - 1;  // prefetch clamp: stay in own chunk (y overwrites dt)
  float dtv[PF_], xv[PF_], zv[PF_];
  f32x4 Bv0[PF_], Bv1[PF_], Cv0[PF_], Cv1[PF_];
#pragma unroll
  for (int i = 0; i < PF_; i++) {
    long o = t0 + i;
    dtv[i] = __half2float(dtb[o * 2048]);
    xv[i] = bf2f(xb[o * DI_]);
    zv[i] = bf2f(zb[o * 2048]);
    Bv0[i] = *(const f32x4*)(bcb + o * 64);
    Bv1[i] = *(const f32x4*)(bcb + o * 64 + 4);
    Cv0[i] = *(const f32x4*)(bcb + o * 64 + 16);
    Cv1[i] = *(const f32x4*)(bcb + o * 64 + 20);
  }
  for (int t = 0; t < LC_; t += PF_) {
#pragma unroll
    for (int u = 0; u < PF_; u++) {
      float dt_c = dtv[u], x_c = xv[u], z_c = zv[u];
      float Bl[8] = {Bv0[u][0], Bv0[u][1], Bv0[u][2], Bv0[u][3],
                     Bv1[u][0], Bv1[u][1], Bv1[u][2], Bv1[u][3]};
      float Cl[8] = {Cv0[u][0], Cv0[u][1], Cv0[u][2], Cv0[u][3],
                     Cv1[u][0], Cv1[u][1], Cv1[u][2], Cv1[u][3]};
      long o = t0 + t + u + PF_;
      if (o > tend) o = tend;
      dtv[u] = __half2float(dtb[o * 2048]);
      xv[u] = bf2f(xb[o * DI_]);
      zv[u] = bf2f(zb[o * 2048]);
      Bv0[u] = *(const f32x4*)(bcb + o * 64);
      Bv1[u] = *(const f32x4*)(bcb + o * 64 + 4);
      Cv0[u] = *(const f32x4*)(bcb + o * 64 + 16);
      Cv1[u] = *(const f32x4*)(bcb + o * 64 + 20);
      float dx = dt_c * x_c;
      float yacc = 0.f;
#pragma unroll
      for (int n = 0; n < 8; n++) {
        float hn = __expf(dt_c * A[n]) * h[n] + dx * Bl[n];
        h[n] = hn;
        yacc += hn * Cl[n];
      }
      yacc += __shfl_xor(yacc, 1, 64);
      if (!half) {
        float sz = z_c / (1.f + __expf(-z_c));
        st1(&yb[(long)(t0 + t + u) * 2048], (yacc + Dd * x_c) * sz);
      }
    }
  }
}

// ---------------- residual + LN + gate (in-place on seq) ----------------
__global__ void k_resid_ln(const bf16* __restrict__ hb, const float* __restrict__ gate,
                           const float* __restrict__ g, const float* __restrict__ bta,
                           bf16* __restrict__ seq) {
  int row = blockIdx.x;
  int t = threadIdx.x;
  float v[2];
#pragma unroll
  for (int i = 0; i < 2; i++) {
    int h = t + i * 256;
    v[i] = bf2f(((const unsigned short*)hb)[(long)row * H_ + h]) +
           bf2f(((const unsigned short*)seq)[(long)row * H_ + h]);
  }
  float lsum = v[0] + v[1];
  float lsq = v[0] * v[0] + v[1] * v[1];
  __shared__ float smA[4], smB[4];
  int lane = t & 63, w = t >> 6;
  lsum = wred_sum(lsum);
  lsq = wred_sum(lsq);
  if (!lane) { smA[w] = lsum; smB[w] = lsq; }
  __syncthreads();
  float tot = smA[0] + smA[1] + smA[2] + smA[3];
  float totq = smB[0] + smB[1] + smB[2] + smB[3];
  float mu = tot * (1.f / H_);
  float var = totq * (1.f / H_) - mu * mu;
  float inv = rsqrtf(fmaxf(var, 0.f) + 1e-12f);
  float gt = gate[row];
#pragma unroll
  for (int i = 0; i < 2; i++) {
    int h = t + i * 256;
    st1(&seq[(long)row * H_ + h], gt * (g[h] * (v[i] - mu) * inv + bta[h]));
  }
}

// ---------------- max pool (two stage) ----------------
__global__ void k_pool1(const bf16* __restrict__ seq, const float* __restrict__ gate,
                        float* __restrict__ part) {
  int blk = blockIdx.x;
  int b = blk >> 4, c = blk & 15;
  int h = threadIdx.x;
  float m = -3.4e38f;
  for (int i = 0; i < 128; i++) {
    long r = (long)b * S_ + c * 128 + i;
    m = fmaxf(m, bf2f(((const unsigned short*)seq)[r * H_ + h]) * gate[r]);
  }
  part[((long)b * 16 + c) * H_ + h] = m;
}
__global__ void k_pool2(const float* __restrict__ part, float* __restrict__ pooled) {
  int idx = blockIdx.x * 256 + threadIdx.x;
  int b = idx >> 9, h = idx & 511;
  float m = -3.4e38f;
#pragma unroll
  for (int c = 0; c < 16; c++) m = fmaxf(m, part[((long)b * 16 + c) * H_ + h]);
  pooled[idx] = m;
}

// ---------------- dense2 + gelu_new ----------------
__global__ void k_feat(const float* __restrict__ pooled, const float* __restrict__ W2,
                       const float* __restrict__ b2, float* __restrict__ feat) {
  int b = blockIdx.x;
  int j = threadIdx.x;
  __shared__ float ps[512];
  ps[j] = pooled[b * 512 + j];
  __syncthreads();
  float acc = b2[j];
  const float* wr = W2 + (long)j * 512;
  for (int k = 0; k < 512; k++) acc += ps[k] * wr[k];
  float x = acc;
  float u = 0.7978845608028654f * (x + 0.044715f * x * x * x);
  feat[b * 512 + j] = 0.5f * x * (1.f + tanhf(u));
}

// ---------------- GroupNorm + FiLM(style) + head ----------------
__global__ void k_head(const float* __restrict__ feat, const float* __restrict__ age_sex,
                       const float* __restrict__ mw, const float* __restrict__ mb,
                       const float* __restrict__ gng, const float* __restrict__ gnb,
                       const float* __restrict__ hw, const float* __restrict__ hb,
                       float* __restrict__ out) {
  int b = blockIdx.x;
  int j = threadIdx.x;
  float f = feat[b * 512 + j];
  __shared__ float sA[8], sB[8];
  int lane = j & 63, w = j >> 6;
  float s1 = wred_sum(f);
  float s2 = wred_sum(f * f);
  if (!lane) { sA[w] = s1; sB[w] = s2; }
  __syncthreads();
  int g = j >> 7;
  float tot = sA[2 * g] + sA[2 * g + 1];
  float totq = sB[2 * g] + sB[2 * g + 1];
  float mu = tot * (1.f / 128.f);
  float var = totq * (1.f / 128.f) - mu * mu;
  float gn = (f - mu) * rsqrtf(fmaxf(var, 0.f) + 1e-5f) * gng[j] + gnb[j];
  float a0 = age_sex[b * 2], a1 = age_sex[b * 2 + 1];
  float sa = a0 * mw[j * 2] + a1 * mw[j * 2 + 1] + mb[j];
  sa = sa > 0.f ? sa : (__expf(sa) - 1.f);
  int j2 = 512 + j;
  float sb = a0 * mw[j2 * 2] + a1 * mw[j2 * 2 + 1] + mb[j2];
  sb = sb > 0.f ? sb : (__expf(sb) - 1.f);
  float feature = (1.f + sa) * gn + sb;
  out[16 + 16384 + b * 512 + j] = feature;
  float l0 = feature * hw[j];
  float l1 = feature * hw[512 + j];
  __syncthreads();
  l0 = wred_sum(l0);
  l1 = wred_sum(l1);
  if (!lane) { sA[w] = l0; sB[w] = l1; }
  __syncthreads();
  if (j == 0) {
    float t0 = 0.f, t1 = 0.f;
#pragma unroll
    for (int i = 0; i < 8; i++) { t0 += sA[i]; t1 += sB[i]; }
    out[b * 2 + 0] = t0 + hb[0];
    out[b * 2 + 1] = t1 + hb[1];
  }
}

__global__ void k_copy(const float* __restrict__ src, float* __restrict__ dst, int n) {
  int i = blockIdx.x * 256 + threadIdx.x;
  if (i < n) dst[i] = src[i];
}

// ---------------- launch ----------------
extern "C" void kernel_launch(void* const* d_in, const int* in_sizes, int n_in,
                              void* d_out, int out_size, void* d_ws, size_t ws_size,
                              hipStream_t stream) {
  const int* ids = (const int*)d_in[0];
  const float* gate = (const float*)d_in[1];
  const float* age_sex = (const float*)d_in[2];
  const float* word_emb = (const float*)d_in[3];
  const float* pos_emb2 = (const float*)d_in[4];
  const float* pe = (const float*)d_in[5];
  const float* emb_ln_g = (const float*)d_in[6];
  const float* emb_ln_b = (const float*)d_in[7];
  const float* in_proj_w = (const float*)d_in[8];
  const float* conv_w = (const float*)d_in[9];
  const float* conv_b = (const float*)d_in[10];
  const float* x_proj_w = (const float*)d_in[11];
  const float* dt_proj_w = (const float*)d_in[12];
  const float* dt_proj_b = (const float*)d_in[13];
  const float* A_log = (const float*)d_in[14];
  const float* D_param = (const float*)d_in[15];
  const float* out_proj_w = (const float*)d_in[16];
  const float* blk_ln_g = (const float*)d_in[17];
  const float* blk_ln_b = (const float*)d_in[18];
  const float* dense2_w = (const float*)d_in[19];
  const float* dense2_b = (const float*)d_in[20];
  const float* male_fc_w = (const float*)d_in[21];
  const float* male_fc_b = (const float*)d_in[22];
  const float* gn_g = (const float*)d_in[23];
  const float* gn_b = (const float*)d_in[24];
  const float* head_w = (const float*)d_in[25];
  const float* head_b = (const float*)d_in[26];
  float* out = (float*)d_out;

  // ws layout (bytes): base 126,320,640; + chunk-scan state -> 130,777,088
  char* w = (char*)d_ws;
  bf16* seq = (bf16*)(w);
  bf16* xz = (bf16*)(w + 16777216);
  bf16* xc = (bf16*)(w + 83886080);
  float* xdb = (float*)(w + 117440512);
  bf16* xdt = (bf16*)(w + 121634816);
  bf16* wi_b = (bf16*)(w + 122683392);
  bf16* wx_b = (bf16*)(w + 124780544);
  bf16* wdt_b = (bf16*)(w + 124911616);
  bf16* wo_b = (bf16*)(w + 124977152);
  float* part = (float*)(w + 126025728);
  float* pooled = (float*)(w + 126287872);
  float* featp = (float*)(w + 126304256);
  float* hf = (float*)(w + 126320640);   // 4,194,304 B
  float* sdt = (float*)(w + 130514944);  //   262,144 B
  const bool chunked = ws_size >= (size_t)130777088;

  k_embed<<<B_ * S_, 256, 0, stream>>>(ids, gate, word_emb, pos_emb2, pe, emb_ln_g,
                                       emb_ln_b, seq);

  const int nWi = 2 * DI_ * H_;
  const int nWx = 64 * DI_;
  const int nWdt = DI_ * DR_;
  const int nWo = H_ * DI_;
  const int cvt_blocks = (nWi + nWx + nWdt + nWo) / 4 / 256;

  for (int l = 0; l < NL_; l++) {
    const float* Wi = in_proj_w + (long)l * nWi;
    const float* cw = conv_w + (long)l * DI_ * DC_;
    const float* cb = conv_b + (long)l * DI_;
    const float* Wx = x_proj_w + (long)l * nWx;
    const float* Wdt = dt_proj_w + (long)l * nWdt;
    const float* bdt = dt_proj_b + (long)l * DI_;
    const float* Al = A_log + (long)l * DI_ * DS_;
    const float* Dl = D_param + (long)l * DI_;
    const float* Wo = out_proj_w + (long)l * nWo;
    const float* bg = blk_ln_g + (long)l * H_;
    const float* bb = blk_ln_b + (long)l * H_;

    k_convert4<<<cvt_blocks, 256, 0, stream>>>(Wi, nWi, Wx, nWx, Wdt, nWdt, Wo, nWo,
                                               wi_b, wx_b, wdt_b, wo_b);

    k_mfma<128, 128, 0, bf16><<<dim3(16, 128), 256, 0, stream>>>(
        (const unsigned short*)seq, H_, (const unsigned short*)wi_b, H_, nullptr,
        xz, 2048, H_, nullptr);
    k_conv<<<(B_ * S_ * DI_) / 256, 256, 0, stream>>>(xz, cw, cb, xc);
    k_mfma<128, 64, 2, float><<<dim3(1, 128), 128, 0, stream>>>(
        (const unsigned short*)xc, DI_, (const unsigned short*)wx_b, DI_, nullptr,
        xdb, 64, DI_, (unsigned short*)xdt);
    k_mfma<128, 128, 1, __half><<<dim3(8, 128), 256, 0, stream>>>(
        (const unsigned short*)xdt, 32, (const unsigned short*)wdt_b, DR_, bdt,
        (__half*)xz, 2048, DR_, nullptr);
    if (chunked) {
      k_scanA<<<2048, 64, 0, stream>>>(xz, xc, xdb, Al, hf, sdt);
      k_scanC<<<2048, 64, 0, stream>>>(xz, xc, xdb, Al, Dl, hf, sdt);
    } else {
      k_scan<<<256, 64, 0, stream>>>(xz, xc, xdb, Al, Dl);
    }
    k_mfma<128, 128, 0, bf16><<<dim3(4, 128), 256, 0, stream>>>(
        (const unsigned short*)xz, 2048, (const unsigned short*)wo_b, DI_, nullptr,
        xc, H_, DI_, nullptr);
    k_resid_ln<<<B_ * S_, 256, 0, stream>>>(xc, gate, bg, bb, seq);
  }

  k_pool1<<<B_ * 16, 512, 0, stream>>>(seq, gate, part);
  k_pool2<<<16, 256, 0, stream>>>(part, pooled);
  k_feat<<<B_, 512, 0, stream>>>(pooled, dense2_w, dense2_b, featp);
  k_head<<<B_, 512, 0, stream>>>(featp, age_sex, male_fc_w, male_fc_b, gn_g, gn_b,
                                 head_w, head_b, out);
  k_copy<<<(B_ * S_ + 255) / 256, 256, 0, stream>>>(gate, out + 16, B_ * S_);
}

// Round 5
// 3512.978 us; speedup vs baseline: 8.4734x; 1.0608x over previous
//
// Round 5: fast-exp selective scan.
// R4 post-mortem: scanC VALU-bound (VALUBusy 73%, HBM 15%, occ 18.5%).
// 8 transcendentals/lane-step ~ half the VALU budget. This problem's
// A_log = log(1..16) => exp(dt*A[n]) = exp(-dt)^(n+1): 1 exp + 11 mul.
// Implemented as runtime-detected wave-uniform fast path (generic 8-exp
// fallback kept, no input values hard-baked). Same in phase-C combine.
// Phase A skips last chunk (h_final unused): grid 1792. Lean f32x4 loops.
#include <hip/hip_runtime.h>
#include <hip/hip_bf16.h>
#include <hip/hip_fp16.h>
#include <math.h>

#define B_ 8
#define S_ 2048
#define H_ 512
#define DI_ 1024
#define DS_ 16
#define DC_ 4
#define DR_ 32
#define NL_ 8
#define NC_ 8
#define LC_ (S_ / NC_)  // 256
#define PF_ 4

typedef __hip_bfloat16 bf16;
typedef short bf16x8 __attribute__((ext_vector_type(8)));
typedef float f32x4 __attribute__((ext_vector_type(4)));

static __device__ __forceinline__ float wred_sum(float v) {
#pragma unroll
  for (int o = 32; o; o >>= 1) v += __shfl_down(v, o, 64);
  return v;
}
static __device__ __forceinline__ float bf2f(unsigned short u) {
  return __uint_as_float(((unsigned)u) << 16);
}
static __device__ __forceinline__ void st1(float* p, float v) { *p = v; }
static __device__ __forceinline__ void st1(bf16* p, float v) { *p = __float2bfloat16(v); }
static __device__ __forceinline__ void st1(__half* p, float v) { *p = __float2half(v); }

static __device__ __forceinline__ void gl_lds16(const unsigned short* g,
                                                unsigned short* l) {
  __builtin_amdgcn_global_load_lds(
      (const __attribute__((address_space(1))) void*)g,
      (__attribute__((address_space(3))) void*)l, 16, 0, 0);
}

// decay p[n] = exp(dt*A[n]).  FAST: A[n] == -(n0+n+1)  =>  p[n] = q^(n0+n+1).
template <bool FAST>
static __device__ __forceinline__ void decay8(float dt, const float* A, int n0,
                                              float* p) {
  if constexpr (FAST) {
    float q = __expf(-dt);
    float q2 = q * q, q4 = q2 * q2, q8 = q4 * q4;
    p[0] = n0 ? q8 * q : q;
#pragma unroll
    for (int n = 1; n < 8; n++) p[n] = p[n - 1] * q;
  } else {
#pragma unroll
    for (int n = 0; n < 8; n++) p[n] = __expf(dt * A[n]);
  }
}

// ---------------- MFMA GEMM: C[M,N] = X[M,K](bf16) @ W[N,K](bf16)^T ----------
template <int BM, int BN, int ACT, typename TC>
__global__ void __launch_bounds__((BM / 64) * (BN / 64) * 64) k_mfma(
    const unsigned short* __restrict__ X, int lda,
    const unsigned short* __restrict__ W, int ldb,
    const float* __restrict__ bias, TC* __restrict__ C, long ldc, int K,
    unsigned short* __restrict__ dtbf) {
  constexpr int NW = (BM / 64) * (BN / 64);
  constexpr int WN = BN / 64;
  constexpr int SEGS = (BM + BN) / 16;
  __shared__ unsigned short As[BM * 32];
  __shared__ unsigned short Bs[BN * 32];
  int tid = threadIdx.x;
  int wave = tid >> 6, lane = tid & 63;
  int wm = wave / WN, wn = wave % WN;
  long row0 = (long)blockIdx.y * BM;
  long col0 = (long)blockIdx.x * BN;
  int srow = lane >> 2;
  int kchunk = (lane & 3) ^ (srow & 3);
  f32x4 acc[4][4] = {};
  for (int k0 = 0; k0 < K; k0 += 32) {
#pragma unroll
    for (int s = wave; s < SEGS; s += NW) {
      if (s < BM / 16) {
        const unsigned short* g =
            X + (row0 + s * 16 + srow) * (long)lda + k0 + kchunk * 8;
        gl_lds16(g, &As[s * 16 * 32]);
      } else {
        int s2 = s - BM / 16;
        const unsigned short* g =
            W + (col0 + s2 * 16 + srow) * (long)ldb + k0 + kchunk * 8;
        gl_lds16(g, &Bs[s2 * 16 * 32]);
      }
    }
    __syncthreads();
    int fr = lane & 15;
    int slot = (lane >> 4) ^ (lane & 3);
    bf16x8 af[4], bfr[4];
#pragma unroll
    for (int i = 0; i < 4; i++)
      af[i] = *(const bf16x8*)&As[(wm * 64 + i * 16 + fr) * 32 + slot * 8];
#pragma unroll
    for (int j = 0; j < 4; j++)
      bfr[j] = *(const bf16x8*)&Bs[(wn * 64 + j * 16 + fr) * 32 + slot * 8];
#pragma unroll
    for (int i = 0; i < 4; i++)
#pragma unroll
      for (int j = 0; j < 4; j++)
        acc[i][j] = __builtin_amdgcn_mfma_f32_16x16x32_bf16(af[i], bfr[j],
                                                            acc[i][j], 0, 0, 0);
    __syncthreads();
  }
#pragma unroll
  for (int i = 0; i < 4; i++) {
#pragma unroll
    for (int j = 0; j < 4; j++) {
      long rbase = row0 + wm * 64 + i * 16 + ((lane >> 4) << 2);
      long c = col0 + wn * 64 + j * 16 + (lane & 15);
#pragma unroll
      for (int reg = 0; reg < 4; reg++) {
        float v = acc[i][j][reg];
        long r = rbase + reg;
        if constexpr (ACT == 1) {
          v += bias[c];
          v = fmaxf(v, 0.f) + log1pf(__expf(-fabsf(v)));  // softplus
        }
        st1(&C[r * ldc + c], v);
        if constexpr (ACT == 2) {
          if (c < 32) st1((bf16*)&dtbf[r * 32 + c], v);
        }
      }
    }
  }
}

// ---------------- weight fp32 -> bf16 conversion ----------------
__global__ void k_convert4(const float* __restrict__ s0, int n0,
                           const float* __restrict__ s1, int n1,
                           const float* __restrict__ s2, int n2,
                           const float* __restrict__ s3, int n3,
                           bf16* __restrict__ d0, bf16* __restrict__ d1,
                           bf16* __restrict__ d2, bf16* __restrict__ d3) {
  int i = blockIdx.x * 256 + threadIdx.x;
  int t0 = n0 >> 2, t1 = t0 + (n1 >> 2), t2 = t1 + (n2 >> 2), t3 = t2 + (n3 >> 2);
  const float* s;
  bf16* d;
  int loc;
  if (i < t0) { s = s0; d = d0; loc = i; }
  else if (i < t1) { s = s1; d = d1; loc = i - t0; }
  else if (i < t2) { s = s2; d = d2; loc = i - t1; }
  else if (i < t3) { s = s3; d = d3; loc = i - t2; }
  else return;
  float4 v = ((const float4*)s)[loc];
  bf16* o = d + (long)loc * 4;
  st1(o + 0, v.x); st1(o + 1, v.y); st1(o + 2, v.z); st1(o + 3, v.w);
}

// ---------------- K1: embedding + LN + gate ----------------
__global__ void k_embed(const int* __restrict__ ids, const float* __restrict__ gate,
                        const float* __restrict__ wemb, const float* __restrict__ pos2,
                        const float* __restrict__ pe, const float* __restrict__ g,
                        const float* __restrict__ bta, bf16* __restrict__ seq) {
  int row = blockIdx.x;
  int s = row % S_;
  int t = threadIdx.x;
  int id = ids[row];
  float v[2];
#pragma unroll
  for (int i = 0; i < 2; i++) {
    int h = t + i * 256;
    v[i] = pos2[s * H_ + h] * wemb[(long)id * H_ + h] + pe[s * H_ + h];
  }
  float lsum = v[0] + v[1];
  float lsq = v[0] * v[0] + v[1] * v[1];
  __shared__ float smA[4], smB[4];
  int lane = t & 63, w = t >> 6;
  lsum = wred_sum(lsum);
  lsq = wred_sum(lsq);
  if (!lane) { smA[w] = lsum; smB[w] = lsq; }
  __syncthreads();
  float tot = smA[0] + smA[1] + smA[2] + smA[3];
  float totq = smB[0] + smB[1] + smB[2] + smB[3];
  float mu = tot * (1.f / H_);
  float var = totq * (1.f / H_) - mu * mu;
  float inv = rsqrtf(fmaxf(var, 0.f) + 1e-12f);
  float gt = gate[row];
#pragma unroll
  for (int i = 0; i < 2; i++) {
    int h = t + i * 256;
    st1(&seq[(long)row * H_ + h], gt * (g[h] * (v[i] - mu) * inv + bta[h]));
  }
}

// ---------------- conv (depthwise causal, DC=4) + silu ----------------
__global__ void k_conv(const bf16* __restrict__ xz, const float* __restrict__ cw,
                       const float* __restrict__ cb, bf16* __restrict__ xc) {
  long idx = (long)blockIdx.x * 256 + threadIdx.x;
  int d = (int)(idx & 1023);
  long bt = idx >> 10;
  int t = (int)(bt & 2047);
  const unsigned short* xbase = (const unsigned short*)xz + (bt - t) * 2048 + d;
  float acc = cb[d];
#pragma unroll
  for (int k = 0; k < 4; k++) {
    int ts = t + k - 3;
    if (ts >= 0) acc += cw[d * 4 + k] * bf2f(xbase[(long)ts * 2048]);
  }
  float s = acc / (1.f + __expf(-acc));
  st1(&xc[idx], s);
}

// ---------------- serial scan (fallback when ws too small) ----------------
__global__ void __launch_bounds__(64) k_scan(
    bf16* __restrict__ xzb, const bf16* __restrict__ xc,
    const float* __restrict__ xdb, const float* __restrict__ Alog,
    const float* __restrict__ Dp) {
  int idx = blockIdx.x * 64 + threadIdx.x;
  int half = idx & 1;
  int p = idx >> 1;
  int d = p & 1023;
  int b = p >> 10;
  int n0 = half * 8;
  float A[8];
#pragma unroll
  for (int n = 0; n < 8; n++) A[n] = -__expf(Alog[d * 16 + n0 + n]);
  float Dd = Dp[d];
  float h[8] = {0, 0, 0, 0, 0, 0, 0, 0};
  const __half* dtb = (const __half*)xzb + (long)b * S_ * 2048 + d;
  const unsigned short* xb = (const unsigned short*)xc + (long)b * S_ * DI_ + d;
  const unsigned short* zb = (const unsigned short*)xzb + (long)b * S_ * 2048 + DI_ + d;
  const float* bcb = xdb + (long)b * S_ * 64 + DR_ + n0;
  bf16* yb = xzb + (long)b * S_ * 2048 + d;
  float dt_c = __half2float(dtb[0]);
  float x_c = bf2f(xb[0]);
  float z_c = bf2f(zb[0]);
  float Bc[8], Cc[8];
#pragma unroll
  for (int n = 0; n < 8; n++) { Bc[n] = bcb[n]; Cc[n] = bcb[16 + n]; }
  for (int t = 0; t < S_; t++) {
    float dt_n = 0.f, x_n = 0.f, z_n = 0.f, Bn[8], Cn[8];
#pragma unroll
    for (int n = 0; n < 8; n++) { Bn[n] = 0.f; Cn[n] = 0.f; }
    if (t + 1 < S_) {
      long o = (long)(t + 1);
      dt_n = __half2float(dtb[o * 2048]);
      x_n = bf2f(xb[o * DI_]);
      z_n = bf2f(zb[o * 2048]);
      const float* bc = bcb + o * 64;
#pragma unroll
      for (int n = 0; n < 8; n++) { Bn[n] = bc[n]; Cn[n] = bc[16 + n]; }
    }
    float dx = dt_c * x_c;
    float yacc = 0.f;
#pragma unroll
    for (int n = 0; n < 8; n++) {
      float hn = __expf(dt_c * A[n]) * h[n] + dx * Bc[n];
      h[n] = hn;
      yacc += hn * Cc[n];
    }
    yacc += __shfl_xor(yacc, 1, 64);
    if (!half) {
      float sz = z_c / (1.f + __expf(-z_c));
      st1(&yb[(long)t * 2048], (yacc + Dd * x_c) * sz);
    }
    dt_c = dt_n; x_c = x_n; z_c = z_n;
#pragma unroll
    for (int n = 0; n < 8; n++) { Bc[n] = Bn[n]; Cc[n] = Cn[n]; }
  }
}

// ---------------- chunked scan phase A body ----------------
template <bool FAST>
static __device__ __forceinline__ void scanA_body(
    const __half* dtb, const unsigned short* xb, const float* bcb,
    const float* A, int n0, int t0, float* h, float& sd) {
  float dtv[PF_], xv[PF_];
  f32x4 Bv0[PF_], Bv1[PF_];
#pragma unroll
  for (int i = 0; i < PF_; i++) {
    long o = t0 + i;
    dtv[i] = __half2float(dtb[o * 2048]);
    xv[i] = bf2f(xb[o * DI_]);
    Bv0[i] = *(const f32x4*)(bcb + o * 64);
    Bv1[i] = *(const f32x4*)(bcb + o * 64 + 4);
  }
  for (int t = 0; t < LC_; t += PF_) {
#pragma unroll
    for (int u = 0; u < PF_; u++) {
      float dt_c = dtv[u], x_c = xv[u];
      f32x4 b0 = Bv0[u], b1 = Bv1[u];
      long o = t0 + t + u + PF_;
      if (o > S_ - 1) o = S_ - 1;  // harmless re-read (read-only in phase A)
      dtv[u] = __half2float(dtb[o * 2048]);
      xv[u] = bf2f(xb[o * DI_]);
      Bv0[u] = *(const f32x4*)(bcb + o * 64);
      Bv1[u] = *(const f32x4*)(bcb + o * 64 + 4);
      sd += dt_c;
      float dx = dt_c * x_c;
      float p[8];
      decay8<FAST>(dt_c, A, n0, p);
#pragma unroll
      for (int n = 0; n < 4; n++) h[n] = p[n] * h[n] + dx * b0[n];
#pragma unroll
      for (int n = 0; n < 4; n++) h[4 + n] = p[4 + n] * h[4 + n] + dx * b1[n];
    }
  }
}

// grid 1792x64: chunks 0..6 only (chunk 7 h_final unused by phase C).
__global__ void __launch_bounds__(64) k_scanA(
    const bf16* __restrict__ xzb, const bf16* __restrict__ xc,
    const float* __restrict__ xdb, const float* __restrict__ Alog,
    float* __restrict__ hf, float* __restrict__ sdt) {
  int idx = blockIdx.x * 64 + threadIdx.x;
  int pf = idx & 16383;
  int c = idx >> 14;
  int half = pf & 1;
  int p = pf >> 1;
  int d = p & 1023;
  int b = p >> 10;
  int n0 = half * 8;
  float A[8];
  bool fast = true;
#pragma unroll
  for (int n = 0; n < 8; n++) {
    A[n] = -__expf(Alog[d * 16 + n0 + n]);
    fast = fast && (fabsf(A[n] + (float)(n0 + n + 1)) < 1e-3f);
  }
  const __half* dtb = (const __half*)xzb + (long)b * S_ * 2048 + d;
  const unsigned short* xb = (const unsigned short*)xc + (long)b * S_ * DI_ + d;
  const float* bcb = xdb + (long)b * S_ * 64 + DR_ + n0;
  int t0 = c * LC_;
  float h[8] = {0, 0, 0, 0, 0, 0, 0, 0};
  float sd = 0.f;
  if (fast) scanA_body<true>(dtb, xb, bcb, A, n0, t0, h, sd);
  else scanA_body<false>(dtb, xb, bcb, A, n0, t0, h, sd);
  float* ho = hf + (long)idx * 8;
#pragma unroll
  for (int n = 0; n < 8; n++) ho[n] = h[n];
  if (!half) sdt[c * 8192 + p] = sd;
}

// ---------------- chunked scan phase C body ----------------
template <bool FAST>
static __device__ __forceinline__ void scanC_body(
    const __half* dtb, const unsigned short* xb, const unsigned short* zb,
    const float* bcb, bf16* yb, const float* A, int n0, int half, int t0,
    float Dd, float* h) {
  int tend = t0 + LC_ - 1;  // prefetch clamp: stay in own chunk (y overwrites dt)
  float dtv[PF_], xv[PF_], zv[PF_];
  f32x4 Bv0[PF_], Bv1[PF_], Cv0[PF_], Cv1[PF_];
#pragma unroll
  for (int i = 0; i < PF_; i++) {
    long o = t0 + i;
    dtv[i] = __half2float(dtb[o * 2048]);
    xv[i] = bf2f(xb[o * DI_]);
    zv[i] = bf2f(zb[o * 2048]);
    Bv0[i] = *(const f32x4*)(bcb + o * 64);
    Bv1[i] = *(const f32x4*)(bcb + o * 64 + 4);
    Cv0[i] = *(const f32x4*)(bcb + o * 64 + 16);
    Cv1[i] = *(const f32x4*)(bcb + o * 64 + 20);
  }
  for (int t = 0; t < LC_; t += PF_) {
#pragma unroll
    for (int u = 0; u < PF_; u++) {
      float dt_c = dtv[u], x_c = xv[u], z_c = zv[u];
      f32x4 b0 = Bv0[u], b1 = Bv1[u], c0 = Cv0[u], c1 = Cv1[u];
      long o = t0 + t + u + PF_;
      if (o > tend) o = tend;
      dtv[u] = __half2float(dtb[o * 2048]);
      xv[u] = bf2f(xb[o * DI_]);
      zv[u] = bf2f(zb[o * 2048]);
      Bv0[u] = *(const f32x4*)(bcb + o * 64);
      Bv1[u] = *(const f32x4*)(bcb + o * 64 + 4);
      Cv0[u] = *(const f32x4*)(bcb + o * 64 + 16);
      Cv1[u] = *(const f32x4*)(bcb + o * 64 + 20);
      float dx = dt_c * x_c;
      float p[8];
      decay8<FAST>(dt_c, A, n0, p);
      float yacc = 0.f;
#pragma unroll
      for (int n = 0; n < 4; n++) {
        float hn = p[n] * h[n] + dx * b0[n];
        h[n] = hn;
        yacc += hn * c0[n];
      }
#pragma unroll
      for (int n = 0; n < 4; n++) {
        float hn = p[4 + n] * h[4 + n] + dx * b1[n];
        h[4 + n] = hn;
        yacc += hn * c1[n];
      }
      yacc += __shfl_xor(yacc, 1, 64);
      if (!half) {
        float sz = z_c / (1.f + __expf(-z_c));
        st1(&yb[(long)(t0 + t + u) * 2048], (yacc + Dd * x_c) * sz);
      }
    }
  }
}

__global__ void __launch_bounds__(64) k_scanC(
    bf16* __restrict__ xzb, const bf16* __restrict__ xc,
    const float* __restrict__ xdb, const float* __restrict__ Alog,
    const float* __restrict__ Dp, const float* __restrict__ hf,
    const float* __restrict__ sdt) {
  int idx = blockIdx.x * 64 + threadIdx.x;
  int pf = idx & 16383;
  int c = idx >> 14;  // wave-uniform
  int half = pf & 1;
  int p = pf >> 1;
  int d = p & 1023;
  int b = p >> 10;
  int n0 = half * 8;
  float A[8];
  bool fast = true;
#pragma unroll
  for (int n = 0; n < 8; n++) {
    A[n] = -__expf(Alog[d * 16 + n0 + n]);
    fast = fast && (fabsf(A[n] + (float)(n0 + n + 1)) < 1e-3f);
  }
  float Dd = Dp[d];
  // h_start = fold of preceding chunk summaries (exp(A*sum_dt) == step product)
  float h[8] = {0, 0, 0, 0, 0, 0, 0, 0};
  if (fast) {
    for (int j = 0; j < c; j++) {
      float sd = sdt[j * 8192 + p];
      const f32x4* hj = (const f32x4*)(hf + ((long)j * 16384 + pf) * 8);
      float pw[8];
      decay8<true>(sd, A, n0, pw);
      f32x4 h0 = hj[0], h1 = hj[1];
#pragma unroll
      for (int n = 0; n < 4; n++) h[n] = pw[n] * h[n] + h0[n];
#pragma unroll
      for (int n = 0; n < 4; n++) h[4 + n] = pw[4 + n] * h[4 + n] + h1[n];
    }
  } else {
    for (int j = 0; j < c; j++) {
      float sd = sdt[j * 8192 + p];
      const f32x4* hj = (const f32x4*)(hf + ((long)j * 16384 + pf) * 8);
      float pw[8];
      decay8<false>(sd, A, n0, pw);
      f32x4 h0 = hj[0], h1 = hj[1];
#pragma unroll
      for (int n = 0; n < 4; n++) h[n] = pw[n] * h[n] + h0[n];
#pragma unroll
      for (int n = 0; n < 4; n++) h[4 + n] = pw[4 + n] * h[4 + n] + h1[n];
    }
  }
  const __half* dtb = (const __half*)xzb + (long)b * S_ * 2048 + d;
  const unsigned short* xb = (const unsigned short*)xc + (long)b * S_ * DI_ + d;
  const unsigned short* zb = (const unsigned short*)xzb + (long)b * S_ * 2048 + DI_ + d;
  const float* bcb = xdb + (long)b * S_ * 64 + DR_ + n0;
  bf16* yb = xzb + (long)b * S_ * 2048 + d;
  int t0 = c * LC_;
  if (fast) scanC_body<true>(dtb, xb, zb, bcb, yb, A, n0, half, t0, Dd, h);
  else scanC_body<false>(dtb, xb, zb, bcb, yb, A, n0, half, t0, Dd, h);
}

// ---------------- residual + LN + gate (in-place on seq) ----------------
__global__ void k_resid_ln(const bf16* __restrict__ hb, const float* __restrict__ gate,
                           const float* __restrict__ g, const float* __restrict__ bta,
                           bf16* __restrict__ seq) {
  int row = blockIdx.x;
  int t = threadIdx.x;
  float v[2];
#pragma unroll
  for (int i = 0; i < 2; i++) {
    int h = t + i * 256;
    v[i] = bf2f(((const unsigned short*)hb)[(long)row * H_ + h]) +
           bf2f(((const unsigned short*)seq)[(long)row * H_ + h]);
  }
  float lsum = v[0] + v[1];
  float lsq = v[0] * v[0] + v[1] * v[1];
  __shared__ float smA[4], smB[4];
  int lane = t & 63, w = t >> 6;
  lsum = wred_sum(lsum);
  lsq = wred_sum(lsq);
  if (!lane) { smA[w] = lsum; smB[w] = lsq; }
  __syncthreads();
  float tot = smA[0] + smA[1] + smA[2] + smA[3];
  float totq = smB[0] + smB[1] + smB[2] + smB[3];
  float mu = tot * (1.f / H_);
  float var = totq * (1.f / H_) - mu * mu;
  float inv = rsqrtf(fmaxf(var, 0.f) + 1e-12f);
  float gt = gate[row];
#pragma unroll
  for (int i = 0; i < 2; i++) {
    int h = t + i * 256;
    st1(&seq[(long)row * H_ + h], gt * (g[h] * (v[i] - mu) * inv + bta[h]));
  }
}

// ---------------- max pool (two stage) ----------------
__global__ void k_pool1(const bf16* __restrict__ seq, const float* __restrict__ gate,
                        float* __restrict__ part) {
  int blk = blockIdx.x;
  int b = blk >> 4, c = blk & 15;
  int h = threadIdx.x;
  float m = -3.4e38f;
  for (int i = 0; i < 128; i++) {
    long r = (long)b * S_ + c * 128 + i;
    m = fmaxf(m, bf2f(((const unsigned short*)seq)[r * H_ + h]) * gate[r]);
  }
  part[((long)b * 16 + c) * H_ + h] = m;
}
__global__ void k_pool2(const float* __restrict__ part, float* __restrict__ pooled) {
  int idx = blockIdx.x * 256 + threadIdx.x;
  int b = idx >> 9, h = idx & 511;
  float m = -3.4e38f;
#pragma unroll
  for (int c = 0; c < 16; c++) m = fmaxf(m, part[((long)b * 16 + c) * H_ + h]);
  pooled[idx] = m;
}

// ---------------- dense2 + gelu_new ----------------
__global__ void k_feat(const float* __restrict__ pooled, const float* __restrict__ W2,
                       const float* __restrict__ b2, float* __restrict__ feat) {
  int b = blockIdx.x;
  int j = threadIdx.x;
  __shared__ float ps[512];
  ps[j] = pooled[b * 512 + j];
  __syncthreads();
  float acc = b2[j];
  const float* wr = W2 + (long)j * 512;
  for (int k = 0; k < 512; k++) acc += ps[k] * wr[k];
  float x = acc;
  float u = 0.7978845608028654f * (x + 0.044715f * x * x * x);
  feat[b * 512 + j] = 0.5f * x * (1.f + tanhf(u));
}

// ---------------- GroupNorm + FiLM(style) + head ----------------
__global__ void k_head(const float* __restrict__ feat, const float* __restrict__ age_sex,
                       const float* __restrict__ mw, const float* __restrict__ mb,
                       const float* __restrict__ gng, const float* __restrict__ gnb,
                       const float* __restrict__ hw, const float* __restrict__ hb,
                       float* __restrict__ out) {
  int b = blockIdx.x;
  int j = threadIdx.x;
  float f = feat[b * 512 + j];
  __shared__ float sA[8], sB[8];
  int lane = j & 63, w = j >> 6;
  float s1 = wred_sum(f);
  float s2 = wred_sum(f * f);
  if (!lane) { sA[w] = s1; sB[w] = s2; }
  __syncthreads();
  int g = j >> 7;
  float tot = sA[2 * g] + sA[2 * g + 1];
  float totq = sB[2 * g] + sB[2 * g + 1];
  float mu = tot * (1.f / 128.f);
  float var = totq * (1.f / 128.f) - mu * mu;
  float gn = (f - mu) * rsqrtf(fmaxf(var, 0.f) + 1e-5f) * gng[j] + gnb[j];
  float a0 = age_sex[b * 2], a1 = age_sex[b * 2 + 1];
  float sa = a0 * mw[j * 2] + a1 * mw[j * 2 + 1] + mb[j];
  sa = sa > 0.f ? sa : (__expf(sa) - 1.f);
  int j2 = 512 + j;
  float sb = a0 * mw[j2 * 2] + a1 * mw[j2 * 2 + 1] + mb[j2];
  sb = sb > 0.f ? sb : (__expf(sb) - 1.f);
  float feature = (1.f + sa) * gn + sb;
  out[16 + 16384 + b * 512 + j] = feature;
  float l0 = feature * hw[j];
  float l1 = feature * hw[512 + j];
  __syncthreads();
  l0 = wred_sum(l0);
  l1 = wred_sum(l1);
  if (!lane) { sA[w] = l0; sB[w] = l1; }
  __syncthreads();
  if (j == 0) {
    float t0 = 0.f, t1 = 0.f;
#pragma unroll
    for (int i = 0; i < 8; i++) { t0 += sA[i]; t1 += sB[i]; }
    out[b * 2 + 0] = t0 + hb[0];
    out[b * 2 + 1] = t1 + hb[1];
  }
}

__global__ void k_copy(const float* __restrict__ src, float* __restrict__ dst, int n) {
  int i = blockIdx.x * 256 + threadIdx.x;
  if (i < n) dst[i] = src[i];
}

// ---------------- launch ----------------
extern "C" void kernel_launch(void* const* d_in, const int* in_sizes, int n_in,
                              void* d_out, int out_size, void* d_ws, size_t ws_size,
                              hipStream_t stream) {
  const int* ids = (const int*)d_in[0];
  const float* gate = (const float*)d_in[1];
  const float* age_sex = (const float*)d_in[2];
  const float* word_emb = (const float*)d_in[3];
  const float* pos_emb2 = (const float*)d_in[4];
  const float* pe = (const float*)d_in[5];
  const float* emb_ln_g = (const float*)d_in[6];
  const float* emb_ln_b = (const float*)d_in[7];
  const float* in_proj_w = (const float*)d_in[8];
  const float* conv_w = (const float*)d_in[9];
  const float* conv_b = (const float*)d_in[10];
  const float* x_proj_w = (const float*)d_in[11];
  const float* dt_proj_w = (const float*)d_in[12];
  const float* dt_proj_b = (const float*)d_in[13];
  const float* A_log = (const float*)d_in[14];
  const float* D_param = (const float*)d_in[15];
  const float* out_proj_w = (const float*)d_in[16];
  const float* blk_ln_g = (const float*)d_in[17];
  const float* blk_ln_b = (const float*)d_in[18];
  const float* dense2_w = (const float*)d_in[19];
  const float* dense2_b = (const float*)d_in[20];
  const float* male_fc_w = (const float*)d_in[21];
  const float* male_fc_b = (const float*)d_in[22];
  const float* gn_g = (const float*)d_in[23];
  const float* gn_b = (const float*)d_in[24];
  const float* head_w = (const float*)d_in[25];
  const float* head_b = (const float*)d_in[26];
  float* out = (float*)d_out;

  // ws layout (bytes): base 126,320,640; + chunk-scan state -> 130,777,088
  char* w = (char*)d_ws;
  bf16* seq = (bf16*)(w);
  bf16* xz = (bf16*)(w + 16777216);
  bf16* xc = (bf16*)(w + 83886080);
  float* xdb = (float*)(w + 117440512);
  bf16* xdt = (bf16*)(w + 121634816);
  bf16* wi_b = (bf16*)(w + 122683392);
  bf16* wx_b = (bf16*)(w + 124780544);
  bf16* wdt_b = (bf16*)(w + 124911616);
  bf16* wo_b = (bf16*)(w + 124977152);
  float* part = (float*)(w + 126025728);
  float* pooled = (float*)(w + 126287872);
  float* featp = (float*)(w + 126304256);
  float* hf = (float*)(w + 126320640);   // 4,194,304 B
  float* sdt = (float*)(w + 130514944);  //   262,144 B
  const bool chunked = ws_size >= (size_t)130777088;

  k_embed<<<B_ * S_, 256, 0, stream>>>(ids, gate, word_emb, pos_emb2, pe, emb_ln_g,
                                       emb_ln_b, seq);

  const int nWi = 2 * DI_ * H_;
  const int nWx = 64 * DI_;
  const int nWdt = DI_ * DR_;
  const int nWo = H_ * DI_;
  const int cvt_blocks = (nWi + nWx + nWdt + nWo) / 4 / 256;

  for (int l = 0; l < NL_; l++) {
    const float* Wi = in_proj_w + (long)l * nWi;
    const float* cw = conv_w + (long)l * DI_ * DC_;
    const float* cb = conv_b + (long)l * DI_;
    const float* Wx = x_proj_w + (long)l * nWx;
    const float* Wdt = dt_proj_w + (long)l * nWdt;
    const float* bdt = dt_proj_b + (long)l * DI_;
    const float* Al = A_log + (long)l * DI_ * DS_;
    const float* Dl = D_param + (long)l * DI_;
    const float* Wo = out_proj_w + (long)l * nWo;
    const float* bg = blk_ln_g + (long)l * H_;
    const float* bb = blk_ln_b + (long)l * H_;

    k_convert4<<<cvt_blocks, 256, 0, stream>>>(Wi, nWi, Wx, nWx, Wdt, nWdt, Wo, nWo,
                                               wi_b, wx_b, wdt_b, wo_b);

    k_mfma<128, 128, 0, bf16><<<dim3(16, 128), 256, 0, stream>>>(
        (const unsigned short*)seq, H_, (const unsigned short*)wi_b, H_, nullptr,
        xz, 2048, H_, nullptr);
    k_conv<<<(B_ * S_ * DI_) / 256, 256, 0, stream>>>(xz, cw, cb, xc);
    k_mfma<128, 64, 2, float><<<dim3(1, 128), 128, 0, stream>>>(
        (const unsigned short*)xc, DI_, (const unsigned short*)wx_b, DI_, nullptr,
        xdb, 64, DI_, (unsigned short*)xdt);
    k_mfma<128, 128, 1, __half><<<dim3(8, 128), 256, 0, stream>>>(
        (const unsigned short*)xdt, 32, (const unsigned short*)wdt_b, DR_, bdt,
        (__half*)xz, 2048, DR_, nullptr);
    if (chunked) {
      k_scanA<<<1792, 64, 0, stream>>>(xz, xc, xdb, Al, hf, sdt);
      k_scanC<<<2048, 64, 0, stream>>>(xz, xc, xdb, Al, Dl, hf, sdt);
    } else {
      k_scan<<<256, 64, 0, stream>>>(xz, xc, xdb, Al, Dl);
    }
    k_mfma<128, 128, 0, bf16><<<dim3(4, 128), 256, 0, stream>>>(
        (const unsigned short*)xz, 2048, (const unsigned short*)wo_b, DI_, nullptr,
        xc, H_, DI_, nullptr);
    k_resid_ln<<<B_ * S_, 256, 0, stream>>>(xc, gate, bg, bb, seq);
  }

  k_pool1<<<B_ * 16, 512, 0, stream>>>(seq, gate, part);
  k_pool2<<<16, 256, 0, stream>>>(part, pooled);
  k_feat<<<B_, 512, 0, stream>>>(pooled, dense2_w, dense2_b, featp);
  k_head<<<B_, 512, 0, stream>>>(featp, age_sex, male_fc_w, male_fc_b, gn_g, gn_b,
                                 head_w, head_b, out);
  k_copy<<<(B_ * S_ + 255) / 256, 256, 0, stream>>>(gate, out + 16, B_ * S_);
}

// Round 6
// 3443.108 us; speedup vs baseline: 8.6454x; 1.0203x over previous
//
// Round 6: scan occupancy + dependency-depth fix.
// R5 post-mortem: exp-cut lowered VALUBusy 73->60% but dur 117->108 only ->
// latency-bound, not VALU-bound. Grid 2048 waves = 8 waves/CU (occ 19.5%),
// decay chain 8-deep serial muls. Fix: NC=16 (4096 blocks = 16 waves/CU),
// log-depth branch-free decay, fp16 chunk summaries (hf/sdt) so ws footprint
// is byte-identical to R5's passing layout (130,777,088).
#include <hip/hip_runtime.h>
#include <hip/hip_bf16.h>
#include <hip/hip_fp16.h>
#include <math.h>

#define B_ 8
#define S_ 2048
#define H_ 512
#define DI_ 1024
#define DS_ 16
#define DC_ 4
#define DR_ 32
#define NL_ 8
#define NC_ 16
#define LC_ (S_ / NC_)  // 128
#define PF_ 4

typedef __hip_bfloat16 bf16;
typedef short bf16x8 __attribute__((ext_vector_type(8)));
typedef float f32x4 __attribute__((ext_vector_type(4)));

static __device__ __forceinline__ float wred_sum(float v) {
#pragma unroll
  for (int o = 32; o; o >>= 1) v += __shfl_down(v, o, 64);
  return v;
}
static __device__ __forceinline__ float bf2f(unsigned short u) {
  return __uint_as_float(((unsigned)u) << 16);
}
static __device__ __forceinline__ void st1(float* p, float v) { *p = v; }
static __device__ __forceinline__ void st1(bf16* p, float v) { *p = __float2bfloat16(v); }
static __device__ __forceinline__ void st1(__half* p, float v) { *p = __float2half(v); }

static __device__ __forceinline__ void gl_lds16(const unsigned short* g,
                                                unsigned short* l) {
  __builtin_amdgcn_global_load_lds(
      (const __attribute__((address_space(1))) void*)g,
      (__attribute__((address_space(3))) void*)l, 16, 0, 0);
}

// decay p[n] = exp(dt*A[n]).  FAST: A[n] == -(n0+n+1) => p[n] = q^(n0+n+1).
// Log-depth, branch-free in n0 (n0 is lane-divergent: half alternates).
template <bool FAST>
static __device__ __forceinline__ void decay8(float dt, const float* A, int n0,
                                              float* p) {
  if constexpr (FAST) {
    float q = __expf(-dt);
    float q2 = q * q, q3 = q2 * q, q4 = q2 * q2;
    float l4 = q4 * q, l5 = q4 * q2, l6 = q4 * q3, q8 = q4 * q4;
    float s = n0 ? q8 : 1.f;
    p[0] = s * q;  p[1] = s * q2; p[2] = s * q3; p[3] = s * q4;
    p[4] = s * l4; p[5] = s * l5; p[6] = s * l6; p[7] = s * q8;
  } else {
#pragma unroll
    for (int n = 0; n < 8; n++) p[n] = __expf(dt * A[n]);
  }
}

// ---------------- MFMA GEMM: C[M,N] = X[M,K](bf16) @ W[N,K](bf16)^T ----------
template <int BM, int BN, int ACT, typename TC>
__global__ void __launch_bounds__((BM / 64) * (BN / 64) * 64) k_mfma(
    const unsigned short* __restrict__ X, int lda,
    const unsigned short* __restrict__ W, int ldb,
    const float* __restrict__ bias, TC* __restrict__ C, long ldc, int K,
    unsigned short* __restrict__ dtbf) {
  constexpr int NW = (BM / 64) * (BN / 64);
  constexpr int WN = BN / 64;
  constexpr int SEGS = (BM + BN) / 16;
  __shared__ unsigned short As[BM * 32];
  __shared__ unsigned short Bs[BN * 32];
  int tid = threadIdx.x;
  int wave = tid >> 6, lane = tid & 63;
  int wm = wave / WN, wn = wave % WN;
  long row0 = (long)blockIdx.y * BM;
  long col0 = (long)blockIdx.x * BN;
  int srow = lane >> 2;
  int kchunk = (lane & 3) ^ (srow & 3);
  f32x4 acc[4][4] = {};
  for (int k0 = 0; k0 < K; k0 += 32) {
#pragma unroll
    for (int s = wave; s < SEGS; s += NW) {
      if (s < BM / 16) {
        const unsigned short* g =
            X + (row0 + s * 16 + srow) * (long)lda + k0 + kchunk * 8;
        gl_lds16(g, &As[s * 16 * 32]);
      } else {
        int s2 = s - BM / 16;
        const unsigned short* g =
            W + (col0 + s2 * 16 + srow) * (long)ldb + k0 + kchunk * 8;
        gl_lds16(g, &Bs[s2 * 16 * 32]);
      }
    }
    __syncthreads();
    int fr = lane & 15;
    int slot = (lane >> 4) ^ (lane & 3);
    bf16x8 af[4], bfr[4];
#pragma unroll
    for (int i = 0; i < 4; i++)
      af[i] = *(const bf16x8*)&As[(wm * 64 + i * 16 + fr) * 32 + slot * 8];
#pragma unroll
    for (int j = 0; j < 4; j++)
      bfr[j] = *(const bf16x8*)&Bs[(wn * 64 + j * 16 + fr) * 32 + slot * 8];
#pragma unroll
    for (int i = 0; i < 4; i++)
#pragma unroll
      for (int j = 0; j < 4; j++)
        acc[i][j] = __builtin_amdgcn_mfma_f32_16x16x32_bf16(af[i], bfr[j],
                                                            acc[i][j], 0, 0, 0);
    __syncthreads();
  }
#pragma unroll
  for (int i = 0; i < 4; i++) {
#pragma unroll
    for (int j = 0; j < 4; j++) {
      long rbase = row0 + wm * 64 + i * 16 + ((lane >> 4) << 2);
      long c = col0 + wn * 64 + j * 16 + (lane & 15);
#pragma unroll
      for (int reg = 0; reg < 4; reg++) {
        float v = acc[i][j][reg];
        long r = rbase + reg;
        if constexpr (ACT == 1) {
          v += bias[c];
          v = fmaxf(v, 0.f) + log1pf(__expf(-fabsf(v)));  // softplus
        }
        st1(&C[r * ldc + c], v);
        if constexpr (ACT == 2) {
          if (c < 32) st1((bf16*)&dtbf[r * 32 + c], v);
        }
      }
    }
  }
}

// ---------------- weight fp32 -> bf16 conversion ----------------
__global__ void k_convert4(const float* __restrict__ s0, int n0,
                           const float* __restrict__ s1, int n1,
                           const float* __restrict__ s2, int n2,
                           const float* __restrict__ s3, int n3,
                           bf16* __restrict__ d0, bf16* __restrict__ d1,
                           bf16* __restrict__ d2, bf16* __restrict__ d3) {
  int i = blockIdx.x * 256 + threadIdx.x;
  int t0 = n0 >> 2, t1 = t0 + (n1 >> 2), t2 = t1 + (n2 >> 2), t3 = t2 + (n3 >> 2);
  const float* s;
  bf16* d;
  int loc;
  if (i < t0) { s = s0; d = d0; loc = i; }
  else if (i < t1) { s = s1; d = d1; loc = i - t0; }
  else if (i < t2) { s = s2; d = d2; loc = i - t1; }
  else if (i < t3) { s = s3; d = d3; loc = i - t2; }
  else return;
  float4 v = ((const float4*)s)[loc];
  bf16* o = d + (long)loc * 4;
  st1(o + 0, v.x); st1(o + 1, v.y); st1(o + 2, v.z); st1(o + 3, v.w);
}

// ---------------- K1: embedding + LN + gate ----------------
__global__ void k_embed(const int* __restrict__ ids, const float* __restrict__ gate,
                        const float* __restrict__ wemb, const float* __restrict__ pos2,
                        const float* __restrict__ pe, const float* __restrict__ g,
                        const float* __restrict__ bta, bf16* __restrict__ seq) {
  int row = blockIdx.x;
  int s = row % S_;
  int t = threadIdx.x;
  int id = ids[row];
  float v[2];
#pragma unroll
  for (int i = 0; i < 2; i++) {
    int h = t + i * 256;
    v[i] = pos2[s * H_ + h] * wemb[(long)id * H_ + h] + pe[s * H_ + h];
  }
  float lsum = v[0] + v[1];
  float lsq = v[0] * v[0] + v[1] * v[1];
  __shared__ float smA[4], smB[4];
  int lane = t & 63, w = t >> 6;
  lsum = wred_sum(lsum);
  lsq = wred_sum(lsq);
  if (!lane) { smA[w] = lsum; smB[w] = lsq; }
  __syncthreads();
  float tot = smA[0] + smA[1] + smA[2] + smA[3];
  float totq = smB[0] + smB[1] + smB[2] + smB[3];
  float mu = tot * (1.f / H_);
  float var = totq * (1.f / H_) - mu * mu;
  float inv = rsqrtf(fmaxf(var, 0.f) + 1e-12f);
  float gt = gate[row];
#pragma unroll
  for (int i = 0; i < 2; i++) {
    int h = t + i * 256;
    st1(&seq[(long)row * H_ + h], gt * (g[h] * (v[i] - mu) * inv + bta[h]));
  }
}

// ---------------- conv (depthwise causal, DC=4) + silu ----------------
__global__ void k_conv(const bf16* __restrict__ xz, const float* __restrict__ cw,
                       const float* __restrict__ cb, bf16* __restrict__ xc) {
  long idx = (long)blockIdx.x * 256 + threadIdx.x;
  int d = (int)(idx & 1023);
  long bt = idx >> 10;
  int t = (int)(bt & 2047);
  const unsigned short* xbase = (const unsigned short*)xz + (bt - t) * 2048 + d;
  float acc = cb[d];
#pragma unroll
  for (int k = 0; k < 4; k++) {
    int ts = t + k - 3;
    if (ts >= 0) acc += cw[d * 4 + k] * bf2f(xbase[(long)ts * 2048]);
  }
  float s = acc / (1.f + __expf(-acc));
  st1(&xc[idx], s);
}

// ---------------- serial scan (fallback when ws too small) ----------------
__global__ void __launch_bounds__(64) k_scan(
    bf16* __restrict__ xzb, const bf16* __restrict__ xc,
    const float* __restrict__ xdb, const float* __restrict__ Alog,
    const float* __restrict__ Dp) {
  int idx = blockIdx.x * 64 + threadIdx.x;
  int half = idx & 1;
  int p = idx >> 1;
  int d = p & 1023;
  int b = p >> 10;
  int n0 = half * 8;
  float A[8];
#pragma unroll
  for (int n = 0; n < 8; n++) A[n] = -__expf(Alog[d * 16 + n0 + n]);
  float Dd = Dp[d];
  float h[8] = {0, 0, 0, 0, 0, 0, 0, 0};
  const __half* dtb = (const __half*)xzb + (long)b * S_ * 2048 + d;
  const unsigned short* xb = (const unsigned short*)xc + (long)b * S_ * DI_ + d;
  const unsigned short* zb = (const unsigned short*)xzb + (long)b * S_ * 2048 + DI_ + d;
  const float* bcb = xdb + (long)b * S_ * 64 + DR_ + n0;
  bf16* yb = xzb + (long)b * S_ * 2048 + d;
  float dt_c = __half2float(dtb[0]);
  float x_c = bf2f(xb[0]);
  float z_c = bf2f(zb[0]);
  float Bc[8], Cc[8];
#pragma unroll
  for (int n = 0; n < 8; n++) { Bc[n] = bcb[n]; Cc[n] = bcb[16 + n]; }
  for (int t = 0; t < S_; t++) {
    float dt_n = 0.f, x_n = 0.f, z_n = 0.f, Bn[8], Cn[8];
#pragma unroll
    for (int n = 0; n < 8; n++) { Bn[n] = 0.f; Cn[n] = 0.f; }
    if (t + 1 < S_) {
      long o = (long)(t + 1);
      dt_n = __half2float(dtb[o * 2048]);
      x_n = bf2f(xb[o * DI_]);
      z_n = bf2f(zb[o * 2048]);
      const float* bc = bcb + o * 64;
#pragma unroll
      for (int n = 0; n < 8; n++) { Bn[n] = bc[n]; Cn[n] = bc[16 + n]; }
    }
    float dx = dt_c * x_c;
    float yacc = 0.f;
#pragma unroll
    for (int n = 0; n < 8; n++) {
      float hn = __expf(dt_c * A[n]) * h[n] + dx * Bc[n];
      h[n] = hn;
      yacc += hn * Cc[n];
    }
    yacc += __shfl_xor(yacc, 1, 64);
    if (!half) {
      float sz = z_c / (1.f + __expf(-z_c));
      st1(&yb[(long)t * 2048], (yacc + Dd * x_c) * sz);
    }
    dt_c = dt_n; x_c = x_n; z_c = z_n;
#pragma unroll
    for (int n = 0; n < 8; n++) { Bc[n] = Bn[n]; Cc[n] = Cn[n]; }
  }
}

// ---------------- chunked scan phase A body ----------------
template <bool FAST>
static __device__ __forceinline__ void scanA_body(
    const __half* dtb, const unsigned short* xb, const float* bcb,
    const float* A, int n0, int t0, float* h, float& sd) {
  float dtv[PF_], xv[PF_];
  f32x4 Bv0[PF_], Bv1[PF_];
#pragma unroll
  for (int i = 0; i < PF_; i++) {
    long o = t0 + i;
    dtv[i] = __half2float(dtb[o * 2048]);
    xv[i] = bf2f(xb[o * DI_]);
    Bv0[i] = *(const f32x4*)(bcb + o * 64);
    Bv1[i] = *(const f32x4*)(bcb + o * 64 + 4);
  }
  for (int t = 0; t < LC_; t += PF_) {
#pragma unroll
    for (int u = 0; u < PF_; u++) {
      float dt_c = dtv[u], x_c = xv[u];
      f32x4 b0 = Bv0[u], b1 = Bv1[u];
      long o = t0 + t + u + PF_;
      if (o > S_ - 1) o = S_ - 1;  // harmless re-read (read-only in phase A)
      dtv[u] = __half2float(dtb[o * 2048]);
      xv[u] = bf2f(xb[o * DI_]);
      Bv0[u] = *(const f32x4*)(bcb + o * 64);
      Bv1[u] = *(const f32x4*)(bcb + o * 64 + 4);
      sd += dt_c;
      float dx = dt_c * x_c;
      float p[8];
      decay8<FAST>(dt_c, A, n0, p);
#pragma unroll
      for (int n = 0; n < 4; n++) h[n] = p[n] * h[n] + dx * b0[n];
#pragma unroll
      for (int n = 0; n < 4; n++) h[4 + n] = p[4 + n] * h[4 + n] + dx * b1[n];
    }
  }
}

// grid 3840x64: chunks 0..14 only (chunk 15 h_final unused by phase C).
__global__ void __launch_bounds__(64) k_scanA(
    const bf16* __restrict__ xzb, const bf16* __restrict__ xc,
    const float* __restrict__ xdb, const float* __restrict__ Alog,
    __half* __restrict__ hf, __half* __restrict__ sdt) {
  int idx = blockIdx.x * 64 + threadIdx.x;
  int pf = idx & 16383;
  int c = idx >> 14;
  int half = pf & 1;
  int p = pf >> 1;
  int d = p & 1023;
  int b = p >> 10;
  int n0 = half * 8;
  float A[8];
  bool fast = true;
#pragma unroll
  for (int n = 0; n < 8; n++) {
    A[n] = -__expf(Alog[d * 16 + n0 + n]);
    fast = fast && (fabsf(A[n] + (float)(n0 + n + 1)) < 1e-3f);
  }
  const __half* dtb = (const __half*)xzb + (long)b * S_ * 2048 + d;
  const unsigned short* xb = (const unsigned short*)xc + (long)b * S_ * DI_ + d;
  const float* bcb = xdb + (long)b * S_ * 64 + DR_ + n0;
  int t0 = c * LC_;
  float h[8] = {0, 0, 0, 0, 0, 0, 0, 0};
  float sd = 0.f;
  if (fast) scanA_body<true>(dtb, xb, bcb, A, n0, t0, h, sd);
  else scanA_body<false>(dtb, xb, bcb, A, n0, t0, h, sd);
  __half* ho = hf + (long)idx * 8;
#pragma unroll
  for (int n = 0; n < 8; n++) st1(&ho[n], h[n]);
  if (!half) st1(&sdt[c * 8192 + p], sd);
}

// ---------------- chunked scan phase C body ----------------
template <bool FAST>
static __device__ __forceinline__ void scanC_body(
    const __half* dtb, const unsigned short* xb, const unsigned short* zb,
    const float* bcb, bf16* yb, const float* A, int n0, int half, int t0,
    float Dd, float* h) {
  int tend = t0 + LC_ - 1;  // prefetch clamp: stay in own chunk (y overwrites dt)
  float dtv[PF_], xv[PF_], zv[PF_];
  f32x4 Bv0[PF_], Bv1[PF_], Cv0[PF_], Cv1[PF_];
#pragma unroll
  for (int i = 0; i < PF_; i++) {
    long o = t0 + i;
    dtv[i] = __half2float(dtb[o * 2048]);
    xv[i] = bf2f(xb[o * DI_]);
    zv[i] = bf2f(zb[o * 2048]);
    Bv0[i] = *(const f32x4*)(bcb + o * 64);
    Bv1[i] = *(const f32x4*)(bcb + o * 64 + 4);
    Cv0[i] = *(const f32x4*)(bcb + o * 64 + 16);
    Cv1[i] = *(const f32x4*)(bcb + o * 64 + 20);
  }
  for (int t = 0; t < LC_; t += PF_) {
#pragma unroll
    for (int u = 0; u < PF_; u++) {
      float dt_c = dtv[u], x_c = xv[u], z_c = zv[u];
      f32x4 b0 = Bv0[u], b1 = Bv1[u], c0 = Cv0[u], c1 = Cv1[u];
      long o = t0 + t + u + PF_;
      if (o > tend) o = tend;
      dtv[u] = __half2float(dtb[o * 2048]);
      xv[u] = bf2f(xb[o * DI_]);
      zv[u] = bf2f(zb[o * 2048]);
      Bv0[u] = *(const f32x4*)(bcb + o * 64);
      Bv1[u] = *(const f32x4*)(bcb + o * 64 + 4);
      Cv0[u] = *(const f32x4*)(bcb + o * 64 + 16);
      Cv1[u] = *(const f32x4*)(bcb + o * 64 + 20);
      float dx = dt_c * x_c;
      float p[8];
      decay8<FAST>(dt_c, A, n0, p);
      float yacc = 0.f;
#pragma unroll
      for (int n = 0; n < 4; n++) {
        float hn = p[n] * h[n] + dx * b0[n];
        h[n] = hn;
        yacc += hn * c0[n];
      }
#pragma unroll
      for (int n = 0; n < 4; n++) {
        float hn = p[4 + n] * h[4 + n] + dx * b1[n];
        h[4 + n] = hn;
        yacc += hn * c1[n];
      }
      yacc += __shfl_xor(yacc, 1, 64);
      if (!half) {
        float sz = z_c / (1.f + __expf(-z_c));
        st1(&yb[(long)(t0 + t + u) * 2048], (yacc + Dd * x_c) * sz);
      }
    }
  }
}

__global__ void __launch_bounds__(64) k_scanC(
    bf16* __restrict__ xzb, const bf16* __restrict__ xc,
    const float* __restrict__ xdb, const float* __restrict__ Alog,
    const float* __restrict__ Dp, const __half* __restrict__ hf,
    const __half* __restrict__ sdt) {
  int idx = blockIdx.x * 64 + threadIdx.x;
  int pf = idx & 16383;
  int c = idx >> 14;  // wave-uniform
  int half = pf & 1;
  int p = pf >> 1;
  int d = p & 1023;
  int b = p >> 10;
  int n0 = half * 8;
  float A[8];
  bool fast = true;
#pragma unroll
  for (int n = 0; n < 8; n++) {
    A[n] = -__expf(Alog[d * 16 + n0 + n]);
    fast = fast && (fabsf(A[n] + (float)(n0 + n + 1)) < 1e-3f);
  }
  float Dd = Dp[d];
  // h_start = fold of preceding chunk summaries (exp(A*sum_dt) == step product)
  float h[8] = {0, 0, 0, 0, 0, 0, 0, 0};
  if (fast) {
    for (int j = 0; j < c; j++) {
      float sd = __half2float(sdt[j * 8192 + p]);
      const __half* hj = hf + ((long)j * 16384 + pf) * 8;
      float pw[8];
      decay8<true>(sd, A, n0, pw);
#pragma unroll
      for (int n = 0; n < 8; n++) h[n] = pw[n] * h[n] + __half2float(hj[n]);
    }
  } else {
    for (int j = 0; j < c; j++) {
      float sd = __half2float(sdt[j * 8192 + p]);
      const __half* hj = hf + ((long)j * 16384 + pf) * 8;
      float pw[8];
      decay8<false>(sd, A, n0, pw);
#pragma unroll
      for (int n = 0; n < 8; n++) h[n] = pw[n] * h[n] + __half2float(hj[n]);
    }
  }
  const __half* dtb = (const __half*)xzb + (long)b * S_ * 2048 + d;
  const unsigned short* xb = (const unsigned short*)xc + (long)b * S_ * DI_ + d;
  const unsigned short* zb = (const unsigned short*)xzb + (long)b * S_ * 2048 + DI_ + d;
  const float* bcb = xdb + (long)b * S_ * 64 + DR_ + n0;
  bf16* yb = xzb + (long)b * S_ * 2048 + d;
  int t0 = c * LC_;
  if (fast) scanC_body<true>(dtb, xb, zb, bcb, yb, A, n0, half, t0, Dd, h);
  else scanC_body<false>(dtb, xb, zb, bcb, yb, A, n0, half, t0, Dd, h);
}

// ---------------- residual + LN + gate (in-place on seq) ----------------
__global__ void k_resid_ln(const bf16* __restrict__ hb, const float* __restrict__ gate,
                           const float* __restrict__ g, const float* __restrict__ bta,
                           bf16* __restrict__ seq) {
  int row = blockIdx.x;
  int t = threadIdx.x;
  float v[2];
#pragma unroll
  for (int i = 0; i < 2; i++) {
    int h = t + i * 256;
    v[i] = bf2f(((const unsigned short*)hb)[(long)row * H_ + h]) +
           bf2f(((const unsigned short*)seq)[(long)row * H_ + h]);
  }
  float lsum = v[0] + v[1];
  float lsq = v[0] * v[0] + v[1] * v[1];
  __shared__ float smA[4], smB[4];
  int lane = t & 63, w = t >> 6;
  lsum = wred_sum(lsum);
  lsq = wred_sum(lsq);
  if (!lane) { smA[w] = lsum; smB[w] = lsq; }
  __syncthreads();
  float tot = smA[0] + smA[1] + smA[2] + smA[3];
  float totq = smB[0] + smB[1] + smB[2] + smB[3];
  float mu = tot * (1.f / H_);
  float var = totq * (1.f / H_) - mu * mu;
  float inv = rsqrtf(fmaxf(var, 0.f) + 1e-12f);
  float gt = gate[row];
#pragma unroll
  for (int i = 0; i < 2; i++) {
    int h = t + i * 256;
    st1(&seq[(long)row * H_ + h], gt * (g[h] * (v[i] - mu) * inv + bta[h]));
  }
}

// ---------------- max pool (two stage) ----------------
__global__ void k_pool1(const bf16* __restrict__ seq, const float* __restrict__ gate,
                        float* __restrict__ part) {
  int blk = blockIdx.x;
  int b = blk >> 4, c = blk & 15;
  int h = threadIdx.x;
  float m = -3.4e38f;
  for (int i = 0; i < 128; i++) {
    long r = (long)b * S_ + c * 128 + i;
    m = fmaxf(m, bf2f(((const unsigned short*)seq)[r * H_ + h]) * gate[r]);
  }
  part[((long)b * 16 + c) * H_ + h] = m;
}
__global__ void k_pool2(const float* __restrict__ part, float* __restrict__ pooled) {
  int idx = blockIdx.x * 256 + threadIdx.x;
  int b = idx >> 9, h = idx & 511;
  float m = -3.4e38f;
#pragma unroll
  for (int c = 0; c < 16; c++) m = fmaxf(m, part[((long)b * 16 + c) * H_ + h]);
  pooled[idx] = m;
}

// ---------------- dense2 + gelu_new ----------------
__global__ void k_feat(const float* __restrict__ pooled, const float* __restrict__ W2,
                       const float* __restrict__ b2, float* __restrict__ feat) {
  int b = blockIdx.x;
  int j = threadIdx.x;
  __shared__ float ps[512];
  ps[j] = pooled[b * 512 + j];
  __syncthreads();
  float acc = b2[j];
  const float* wr = W2 + (long)j * 512;
  for (int k = 0; k < 512; k++) acc += ps[k] * wr[k];
  float x = acc;
  float u = 0.7978845608028654f * (x + 0.044715f * x * x * x);
  feat[b * 512 + j] = 0.5f * x * (1.f + tanhf(u));
}

// ---------------- GroupNorm + FiLM(style) + head ----------------
__global__ void k_head(const float* __restrict__ feat, const float* __restrict__ age_sex,
                       const float* __restrict__ mw, const float* __restrict__ mb,
                       const float* __restrict__ gng, const float* __restrict__ gnb,
                       const float* __restrict__ hw, const float* __restrict__ hb,
                       float* __restrict__ out) {
  int b = blockIdx.x;
  int j = threadIdx.x;
  float f = feat[b * 512 + j];
  __shared__ float sA[8], sB[8];
  int lane = j & 63, w = j >> 6;
  float s1 = wred_sum(f);
  float s2 = wred_sum(f * f);
  if (!lane) { sA[w] = s1; sB[w] = s2; }
  __syncthreads();
  int g = j >> 7;
  float tot = sA[2 * g] + sA[2 * g + 1];
  float totq = sB[2 * g] + sB[2 * g + 1];
  float mu = tot * (1.f / 128.f);
  float var = totq * (1.f / 128.f) - mu * mu;
  float gn = (f - mu) * rsqrtf(fmaxf(var, 0.f) + 1e-5f) * gng[j] + gnb[j];
  float a0 = age_sex[b * 2], a1 = age_sex[b * 2 + 1];
  float sa = a0 * mw[j * 2] + a1 * mw[j * 2 + 1] + mb[j];
  sa = sa > 0.f ? sa : (__expf(sa) - 1.f);
  int j2 = 512 + j;
  float sb = a0 * mw[j2 * 2] + a1 * mw[j2 * 2 + 1] + mb[j2];
  sb = sb > 0.f ? sb : (__expf(sb) - 1.f);
  float feature = (1.f + sa) * gn + sb;
  out[16 + 16384 + b * 512 + j] = feature;
  float l0 = feature * hw[j];
  float l1 = feature * hw[512 + j];
  __syncthreads();
  l0 = wred_sum(l0);
  l1 = wred_sum(l1);
  if (!lane) { sA[w] = l0; sB[w] = l1; }
  __syncthreads();
  if (j == 0) {
    float t0 = 0.f, t1 = 0.f;
#pragma unroll
    for (int i = 0; i < 8; i++) { t0 += sA[i]; t1 += sB[i]; }
    out[b * 2 + 0] = t0 + hb[0];
    out[b * 2 + 1] = t1 + hb[1];
  }
}

__global__ void k_copy(const float* __restrict__ src, float* __restrict__ dst, int n) {
  int i = blockIdx.x * 256 + threadIdx.x;
  if (i < n) dst[i] = src[i];
}

// ---------------- launch ----------------
extern "C" void kernel_launch(void* const* d_in, const int* in_sizes, int n_in,
                              void* d_out, int out_size, void* d_ws, size_t ws_size,
                              hipStream_t stream) {
  const int* ids = (const int*)d_in[0];
  const float* gate = (const float*)d_in[1];
  const float* age_sex = (const float*)d_in[2];
  const float* word_emb = (const float*)d_in[3];
  const float* pos_emb2 = (const float*)d_in[4];
  const float* pe = (const float*)d_in[5];
  const float* emb_ln_g = (const float*)d_in[6];
  const float* emb_ln_b = (const float*)d_in[7];
  const float* in_proj_w = (const float*)d_in[8];
  const float* conv_w = (const float*)d_in[9];
  const float* conv_b = (const float*)d_in[10];
  const float* x_proj_w = (const float*)d_in[11];
  const float* dt_proj_w = (const float*)d_in[12];
  const float* dt_proj_b = (const float*)d_in[13];
  const float* A_log = (const float*)d_in[14];
  const float* D_param = (const float*)d_in[15];
  const float* out_proj_w = (const float*)d_in[16];
  const float* blk_ln_g = (const float*)d_in[17];
  const float* blk_ln_b = (const float*)d_in[18];
  const float* dense2_w = (const float*)d_in[19];
  const float* dense2_b = (const float*)d_in[20];
  const float* male_fc_w = (const float*)d_in[21];
  const float* male_fc_b = (const float*)d_in[22];
  const float* gn_g = (const float*)d_in[23];
  const float* gn_b = (const float*)d_in[24];
  const float* head_w = (const float*)d_in[25];
  const float* head_b = (const float*)d_in[26];
  float* out = (float*)d_out;

  // ws layout (bytes): identical footprint to R5 (130,777,088); hf/sdt now fp16
  char* w = (char*)d_ws;
  bf16* seq = (bf16*)(w);
  bf16* xz = (bf16*)(w + 16777216);
  bf16* xc = (bf16*)(w + 83886080);
  float* xdb = (float*)(w + 117440512);
  bf16* xdt = (bf16*)(w + 121634816);
  bf16* wi_b = (bf16*)(w + 122683392);
  bf16* wx_b = (bf16*)(w + 124780544);
  bf16* wdt_b = (bf16*)(w + 124911616);
  bf16* wo_b = (bf16*)(w + 124977152);
  float* part = (float*)(w + 126025728);
  float* pooled = (float*)(w + 126287872);
  float* featp = (float*)(w + 126304256);
  __half* hf = (__half*)(w + 126320640);   // 15*16384*8*2 = 3,932,160 B (slot 4 MiB)
  __half* sdt = (__half*)(w + 130514944);  // 15*8192*2 = 245,760 B (slot 256 KiB)
  const bool chunked = ws_size >= (size_t)130777088;

  k_embed<<<B_ * S_, 256, 0, stream>>>(ids, gate, word_emb, pos_emb2, pe, emb_ln_g,
                                       emb_ln_b, seq);

  const int nWi = 2 * DI_ * H_;
  const int nWx = 64 * DI_;
  const int nWdt = DI_ * DR_;
  const int nWo = H_ * DI_;
  const int cvt_blocks = (nWi + nWx + nWdt + nWo) / 4 / 256;

  for (int l = 0; l < NL_; l++) {
    const float* Wi = in_proj_w + (long)l * nWi;
    const float* cw = conv_w + (long)l * DI_ * DC_;
    const float* cb = conv_b + (long)l * DI_;
    const float* Wx = x_proj_w + (long)l * nWx;
    const float* Wdt = dt_proj_w + (long)l * nWdt;
    const float* bdt = dt_proj_b + (long)l * DI_;
    const float* Al = A_log + (long)l * DI_ * DS_;
    const float* Dl = D_param + (long)l * DI_;
    const float* Wo = out_proj_w + (long)l * nWo;
    const float* bg = blk_ln_g + (long)l * H_;
    const float* bb = blk_ln_b + (long)l * H_;

    k_convert4<<<cvt_blocks, 256, 0, stream>>>(Wi, nWi, Wx, nWx, Wdt, nWdt, Wo, nWo,
                                               wi_b, wx_b, wdt_b, wo_b);

    k_mfma<128, 128, 0, bf16><<<dim3(16, 128), 256, 0, stream>>>(
        (const unsigned short*)seq, H_, (const unsigned short*)wi_b, H_, nullptr,
        xz, 2048, H_, nullptr);
    k_conv<<<(B_ * S_ * DI_) / 256, 256, 0, stream>>>(xz, cw, cb, xc);
    k_mfma<128, 64, 2, float><<<dim3(1, 128), 128, 0, stream>>>(
        (const unsigned short*)xc, DI_, (const unsigned short*)wx_b, DI_, nullptr,
        xdb, 64, DI_, (unsigned short*)xdt);
    k_mfma<128, 128, 1, __half><<<dim3(8, 128), 256, 0, stream>>>(
        (const unsigned short*)xdt, 32, (const unsigned short*)wdt_b, DR_, bdt,
        (__half*)xz, 2048, DR_, nullptr);
    if (chunked) {
      k_scanA<<<(NC_ - 1) * 256, 64, 0, stream>>>(xz, xc, xdb, Al, hf, sdt);
      k_scanC<<<NC_ * 256, 64, 0, stream>>>(xz, xc, xdb, Al, Dl, hf, sdt);
    } else {
      k_scan<<<256, 64, 0, stream>>>(xz, xc, xdb, Al, Dl);
    }
    k_mfma<128, 128, 0, bf16><<<dim3(4, 128), 256, 0, stream>>>(
        (const unsigned short*)xz, 2048, (const unsigned short*)wo_b, DI_, nullptr,
        xc, H_, DI_, nullptr);
    k_resid_ln<<<B_ * S_, 256, 0, stream>>>(xc, gate, bg, bb, seq);
  }

  k_pool1<<<B_ * 16, 512, 0, stream>>>(seq, gate, part);
  k_pool2<<<16, 256, 0, stream>>>(part, pooled);
  k_feat<<<B_, 512, 0, stream>>>(pooled, dense2_w, dense2_b, featp);
  k_head<<<B_, 512, 0, stream>>>(featp, age_sex, male_fc_w, male_fc_b, gn_g, gn_b,
                                 head_w, head_b, out);
  k_copy<<<(B_ * S_ + 255) / 256, 256, 0, stream>>>(gate, out + 16, B_ * S_);
}